// Round 19
// baseline (309.537 us; speedup 1.0000x reference)
//
#include <hip/hip_runtime.h>

#define NN  10000
#define HD  128
#define EE  160000
#define RD  32
#define NH  (NN * HD)

typedef __attribute__((ext_vector_type(8))) short short8_t;
typedef __attribute__((ext_vector_type(4))) float f32x4_t;
typedef __attribute__((ext_vector_type(4))) int   int4_t;

// fast silu: v_rcp_f32 (~1ulp) instead of exact-div sequence
__device__ __forceinline__ float silu_f(float z) {
    return z * __builtin_amdgcn_rcpf(1.0f + __expf(-z));
}
__device__ __forceinline__ short f2b(float v) {   // RNE fp32->bf16
    unsigned u = __float_as_uint(v);
    unsigned r = (u + 0x7FFFu + ((u >> 16) & 1u)) >> 16;
    return (short)r;
}
__device__ __forceinline__ float b2f(short s) {
    return __uint_as_float(((unsigned)(unsigned short)s) << 16);
}
// HW packed convert: bits[15:0]=bf16(a), bits[31:16]=bf16(b), RNE.
__device__ __forceinline__ unsigned cvt_pk(float a, float b) {
    unsigned r;
    asm("v_cvt_pk_bf16_f32 %0, %1, %2" : "=v"(r) : "v"(a), "v"(b));
    return r;
}
__device__ __forceinline__ float ldy(const float* p) { return *p; }
__device__ __forceinline__ float ldy(const short* p) { return b2f(*p); }

// ---------------------------------------------------------------------------
// Weight conversion + edge histogram folded into tail blocks (grid 1553).
// ---------------------------------------------------------------------------
__global__ __launch_bounds__(256) void k_wconv(
    const float* __restrict__ W1, const float* __restrict__ W2,
    const float* __restrict__ W3,
    const float* __restrict__ Wt0, const float* __restrict__ Wt1,
    const float* __restrict__ Wt2, const float* __restrict__ Wt3,
    const float* __restrict__ Wt4, const float* __restrict__ Wt5,
    const int* __restrict__ EI,   int* __restrict__ cnt,
    short* __restrict__ W1b, short* __restrict__ W2b, short* __restrict__ W3b,
    short* __restrict__ WtPh, short* __restrict__ WtPl,
    short* __restrict__ WtFh, short* __restrict__ WtFl)
{
    if (blockIdx.x >= 928) {              // histogram tail: 625 blocks
        const int e = (blockIdx.x - 928) * 256 + threadIdx.x;
        atomicAdd(&cnt[EI[e]], 1);
        return;
    }
    const int i = blockIdx.x * 256 + threadIdx.x;
    if (i < 8192) {                       // layer1: ct<8, kb<2, K_in=34
        const int j = i & 7, lane = (i >> 3) & 63;
        const int kb = (i >> 9) & 1, ct = i >> 10;
        const int n = ct * 16 + (lane & 15);
        const int k = kb * 32 + (lane >> 4) * 8 + j;
        W1b[i] = (k < 34) ? f2b(W1[n * 34 + k]) : (short)0;
        return;
    }
    int j2 = i - 8192;
    if (j2 < 32768) {                     // layer2: ct<16, kb<4, K_in=128
        const int j = j2 & 7, lane = (j2 >> 3) & 63;
        const int kb = (j2 >> 9) & 3, ct = j2 >> 11;
        const int n = ct * 16 + (lane & 15);
        const int k = kb * 32 + (lane >> 4) * 8 + j;
        W2b[j2] = f2b(W2[n * 128 + k]);
        return;
    }
    j2 -= 32768;
    if (j2 < 98304) {                     // layer3: ct<24, kb<8, K_in=256
        const int j = j2 & 7, lane = (j2 >> 3) & 63;
        const int kb = (j2 >> 9) & 7, ct = j2 >> 12;
        const int n = ct * 16 + (lane & 15);
        const int k = kb * 32 + (lane >> 4) * 8 + j;
        W3b[j2] = f2b(W3[n * 256 + k]);
        return;
    }
    j2 -= 98304;
    if (j2 < 6 * 16384) {
        const int m = j2 >> 14, idx = j2 & 16383;
        const float* src = (m == 0) ? Wt0 : (m == 1) ? Wt1 : (m == 2) ? Wt2
                         : (m == 3) ? Wt3 : (m == 4) ? Wt4 : Wt5;
        const float w = src[idx];
        const short hi = f2b(w);
        const short lo = f2b(w - b2f(hi));
        if (m < 3) { WtPh[m * 16384 + idx] = hi; WtPl[m * 16384 + idx] = lo; }
        else       { WtFh[(m - 3) * 16384 + idx] = hi; WtFl[(m - 3) * 16384 + idx] = lo; }
    }
}

// ---------------------------------------------------------------------------
// k_mix_prep<YBF16>: decompose X, channel-mix with WtP (hi/lo split).
// ---------------------------------------------------------------------------
template <bool YBF16>
__global__ __launch_bounds__(512, 4) void k_mix_prep(
    const float* __restrict__ X,
    const short* __restrict__ Wh, const short* __restrict__ Wl,
    float* __restrict__ Yf, short* __restrict__ ybf)
{
    extern __shared__ __align__(16) char smem[];   // 73728 B
    short* sBh = (short*)smem;
    short* sBl = sBh + 144 * 128;
    float* sC  = (float*)smem;

    const int tid = threadIdx.x;
    const int n0  = blockIdx.x * 16;

#pragma unroll 2
    for (int i = 0; i < 4; i++) {
        const int p  = i * 512 + tid;
        const int nl = p >> 7, h = p & 127;
        const float* t = X + ((size_t)((n0 + nl) * HD + h)) * 9;
        float T[9];
#pragma unroll
        for (int q = 0; q < 9; q++) T[q] = t[q];
        float nrm = 0.f;
#pragma unroll
        for (int q = 0; q < 9; q++) nrm = fmaf(T[q], T[q], nrm);
        const float inv = 1.0f / (nrm + 1.0f);
#pragma unroll
        for (int q = 0; q < 9; q++) T[q] *= inv;
        const float I = (T[0] + T[4] + T[8]) * (1.0f / 3.0f);
        float dec[9];
        dec[0] = I;
        dec[1] = 0.5f * (T[7] - T[5]);
        dec[2] = 0.5f * (T[2] - T[6]);
        dec[3] = 0.5f * (T[3] - T[1]);
        dec[4] = T[0] - I;
        dec[5] = 0.5f * (T[1] + T[3]);
        dec[6] = 0.5f * (T[2] + T[6]);
        dec[7] = T[4] - I;
        dec[8] = 0.5f * (T[5] + T[7]);
        const int sw = (nl & 7) << 3;
        const int hx = h ^ sw;
#pragma unroll
        for (int c = 0; c < 9; c++) {
            const float v  = dec[c];
            const short hi = f2b(v);
            const short lo = f2b(v - b2f(hi));
            const int idx = (c * 16 + nl) * 128 + hx;
            sBh[idx] = hi;
            sBl[idx] = lo;
        }
    }
    __syncthreads();

    const int lane = tid & 63, wid = tid >> 6;
    const int l15 = lane & 15, g = lane >> 4;
    f32x4_t acc[9];
#pragma unroll
    for (int c = 0; c < 9; c++) acc[c] = {0.f, 0.f, 0.f, 0.f};

    const int bsw = (l15 & 7) << 3;
    const int o   = wid * 16 + l15;
#pragma unroll
    for (int k = 0; k < 4; k++) {
        const int k0  = k * 32 + g * 8;
        const int ksw = k0 ^ bsw;
#pragma unroll
        for (int w = 0; w < 3; w++) {
            const size_t aoff = (size_t)w * 16384 + (size_t)o * 128 + k0;
            const short8_t Ah = *(const short8_t*)(Wh + aoff);
            const short8_t Al = *(const short8_t*)(Wl + aoff);
            const int ct0 = (w == 0) ? 0 : (w == 1 ? 1 : 4);
            const int ctn = (w == 0) ? 1 : (w == 1 ? 3 : 5);
            for (int cc = 0; cc < ctn; cc++) {
                const int ct = ct0 + cc;
                const int boff = (ct * 16 + l15) * 128 + ksw;
                const short8_t Bh = *(const short8_t*)&sBh[boff];
                const short8_t Bl = *(const short8_t*)&sBl[boff];
                acc[ct] = __builtin_amdgcn_mfma_f32_16x16x32_bf16(Al, Bh, acc[ct], 0, 0, 0);
                acc[ct] = __builtin_amdgcn_mfma_f32_16x16x32_bf16(Ah, Bl, acc[ct], 0, 0, 0);
                acc[ct] = __builtin_amdgcn_mfma_f32_16x16x32_bf16(Ah, Bh, acc[ct], 0, 0, 0);
            }
        }
    }
    __syncthreads();

    const int csw = (l15 & 7) << 2;
    {
        const int o0 = wid * 16 + g * 4;
#pragma unroll
        for (int ct = 0; ct < 9; ct++)
            *(f32x4_t*)&sC[(ct * 16 + l15) * 128 + (o0 ^ csw)] = acc[ct];
    }
    __syncthreads();

    for (int i = tid; i < 144 * 32; i += 512) {
        const int row = i >> 5, q = i & 31;
        const int c = row >> 4, nl = row & 15;
        const int sw = (nl & 7) << 2;
        const f32x4_t v = *(const f32x4_t*)&sC[row * 128 + ((q * 4) ^ sw)];
        const size_t oo = (size_t)c * NH + (size_t)(n0 + nl) * HD + q * 4;
        if constexpr (YBF16) {
            uint2 u;
            u.x = cvt_pk(v[0], v[1]);
            u.y = cvt_pk(v[2], v[3]);
            *(uint2*)&ybf[oo] = u;
        } else {
            *(f32x4_t*)&Yf[oo] = v;
        }
    }
}

// ---------------------------------------------------------------------------
// k_mix_fin<YT, MT>: M = msg*Y + Y*msg; decompose/normalize; mix WtF; out.
// ---------------------------------------------------------------------------
template <typename YT, typename MT>
__global__ __launch_bounds__(512, 4) void k_mix_fin(
    const float* __restrict__ X,
    const YT* __restrict__ Yp, const MT* __restrict__ Mp,
    const short* __restrict__ Wh, const short* __restrict__ Wl,
    float* __restrict__ outp)
{
    extern __shared__ __align__(16) char smem[];   // 73728 B
    short* sBh = (short*)smem;
    short* sBl = sBh + 144 * 128;
    float* sC  = (float*)smem;

    const int tid = threadIdx.x;
    const int n0  = blockIdx.x * 16;

#pragma unroll 2
    for (int i = 0; i < 4; i++) {
        const int p  = i * 512 + tid;
        const int nl = p >> 7, h = p & 127;
        const int basep = (n0 + nl) * HD + h;
        float yv[9], mv[9];
#pragma unroll
        for (int c = 0; c < 9; c++) {
            yv[c] = ldy(Yp + (size_t)c * NH + basep);
            mv[c] = ldy(Mp + (size_t)c * NH + basep);
        }
        float Yt[9], G[9];
        {
            const float I = yv[0], a0 = yv[1], a1 = yv[2], a2 = yv[3];
            const float s00 = yv[4], s01 = yv[5], s02 = yv[6], s11 = yv[7], s12 = yv[8];
            const float s22 = -s00 - s11;
            Yt[0] = I + s00; Yt[1] = s01 - a2; Yt[2] = s02 + a1;
            Yt[3] = s01 + a2; Yt[4] = I + s11; Yt[5] = s12 - a0;
            Yt[6] = s02 - a1; Yt[7] = s12 + a0; Yt[8] = I + s22;
        }
        {
            const float I = mv[0], a0 = mv[1], a1 = mv[2], a2 = mv[3];
            const float s00 = mv[4], s01 = mv[5], s02 = mv[6], s11 = mv[7], s12 = mv[8];
            const float s22 = -s00 - s11;
            G[0] = I + s00; G[1] = s01 - a2; G[2] = s02 + a1;
            G[3] = s01 + a2; G[4] = I + s11; G[5] = s12 - a0;
            G[6] = s02 - a1; G[7] = s12 + a0; G[8] = I + s22;
        }
        float M[9];
#pragma unroll
        for (int r = 0; r < 3; r++)
#pragma unroll
            for (int cc = 0; cc < 3; cc++) {
                float a = 0.f;
#pragma unroll
                for (int k = 0; k < 3; k++)
                    a += G[r * 3 + k] * Yt[k * 3 + cc]
                       + Yt[r * 3 + k] * G[k * 3 + cc];
                M[r * 3 + cc] = a;
            }
        const float I2 = (M[0] + M[4] + M[8]) * (1.0f / 3.0f);
        const float a0 = 0.5f * (M[7] - M[5]);
        const float a1 = 0.5f * (M[2] - M[6]);
        const float a2 = 0.5f * (M[3] - M[1]);
        const float s00 = M[0] - I2, s11 = M[4] - I2;
        const float s01 = 0.5f * (M[1] + M[3]);
        const float s02 = 0.5f * (M[2] + M[6]);
        const float s12 = 0.5f * (M[5] + M[7]);
        const float s22 = -s00 - s11;
        const float nrm = 2.f * (a0 * a0 + a1 * a1 + a2 * a2)
                        + (s00 * s00 + s11 * s11 + s22 * s22)
                        + 2.f * (s01 * s01 + s02 * s02 + s12 * s12)
                        + 3.f * I2 * I2;
        const float inv = 1.0f / (nrm + 1.0f);
        float dec[9];
        dec[0] = I2 * inv;  dec[1] = a0 * inv;  dec[2] = a1 * inv;
        dec[3] = a2 * inv;  dec[4] = s00 * inv; dec[5] = s01 * inv;
        dec[6] = s02 * inv; dec[7] = s11 * inv; dec[8] = s12 * inv;

        const int sw = (nl & 7) << 3;
        const int hx = h ^ sw;
#pragma unroll
        for (int c = 0; c < 9; c++) {
            const float v  = dec[c];
            const short hi = f2b(v);
            const short lo = f2b(v - b2f(hi));
            const int idx = (c * 16 + nl) * 128 + hx;
            sBh[idx] = hi;
            sBl[idx] = lo;
        }
    }
    __syncthreads();

    const int lane = tid & 63, wid = tid >> 6;
    const int l15 = lane & 15, g = lane >> 4;
    f32x4_t acc[9];
#pragma unroll
    for (int c = 0; c < 9; c++) acc[c] = {0.f, 0.f, 0.f, 0.f};

    const int bsw = (l15 & 7) << 3;
    const int o   = wid * 16 + l15;
#pragma unroll
    for (int k = 0; k < 4; k++) {
        const int k0  = k * 32 + g * 8;
        const int ksw = k0 ^ bsw;
#pragma unroll
        for (int w = 0; w < 3; w++) {
            const size_t aoff = (size_t)w * 16384 + (size_t)o * 128 + k0;
            const short8_t Ah = *(const short8_t*)(Wh + aoff);
            const short8_t Al = *(const short8_t*)(Wl + aoff);
            const int ct0 = (w == 0) ? 0 : (w == 1 ? 1 : 4);
            const int ctn = (w == 0) ? 1 : (w == 1 ? 3 : 5);
            for (int cc = 0; cc < ctn; cc++) {
                const int ct = ct0 + cc;
                const int boff = (ct * 16 + l15) * 128 + ksw;
                const short8_t Bh = *(const short8_t*)&sBh[boff];
                const short8_t Bl = *(const short8_t*)&sBl[boff];
                acc[ct] = __builtin_amdgcn_mfma_f32_16x16x32_bf16(Al, Bh, acc[ct], 0, 0, 0);
                acc[ct] = __builtin_amdgcn_mfma_f32_16x16x32_bf16(Ah, Bl, acc[ct], 0, 0, 0);
                acc[ct] = __builtin_amdgcn_mfma_f32_16x16x32_bf16(Ah, Bh, acc[ct], 0, 0, 0);
            }
        }
    }
    __syncthreads();

    const int csw = (l15 & 7) << 2;
    {
        const int o0 = wid * 16 + g * 4;
#pragma unroll
        for (int ct = 0; ct < 9; ct++)
            *(f32x4_t*)&sC[(ct * 16 + l15) * 128 + (o0 ^ csw)] = acc[ct];
    }
    __syncthreads();

#pragma unroll 2
    for (int i = 0; i < 4; i++) {
        const int p  = i * 512 + tid;
        const int nl = p >> 7, oo = p & 127;
        const int sw = (nl & 7) << 2;
        const int ox = oo ^ sw;
        float a9[9];
#pragma unroll
        for (int c = 0; c < 9; c++) a9[c] = sC[(c * 16 + nl) * 128 + ox];
        float D[9];
        {
            const float I = a9[0], a0 = a9[1], a1 = a9[2], a2 = a9[3];
            const float s00 = a9[4], s01 = a9[5], s02 = a9[6];
            const float s11 = a9[7], s12 = a9[8];
            const float s22 = -s00 - s11;
            D[0] = I + s00; D[1] = s01 - a2; D[2] = s02 + a1;
            D[3] = s01 + a2; D[4] = I + s11; D[5] = s12 - a0;
            D[6] = s02 - a1; D[7] = s12 + a0; D[8] = I + s22;
        }
        const size_t xbase = ((size_t)((n0 + nl) * HD + oo)) * 9;
        float T[9];
#pragma unroll
        for (int q = 0; q < 9; q++) T[q] = X[xbase + q];
        float nrm = 0.f;
#pragma unroll
        for (int q = 0; q < 9; q++) nrm = fmaf(T[q], T[q], nrm);
        const float inv = 1.0f / (nrm + 1.0f);
        float* op = outp + xbase;
#pragma unroll
        for (int r = 0; r < 3; r++)
#pragma unroll
            for (int cc = 0; cc < 3; cc++) {
                float dd2 = 0.f;
#pragma unroll
                for (int k = 0; k < 3; k++)
                    dd2 = fmaf(D[r * 3 + k], D[k * 3 + cc], dd2);
                op[r * 3 + cc] = T[r * 3 + cc] * inv + D[r * 3 + cc] + dd2;
            }
    }
}

// ---------------------------------------------------------------------------
// CSR scan + fill.
// ---------------------------------------------------------------------------
__global__ __launch_bounds__(256) void k_scan(const int* __restrict__ cnt,
                                              int* __restrict__ offs,
                                              int* __restrict__ cur)
{
    __shared__ int part[256];
    const int tid = threadIdx.x;
    const int per = (NN + 255) / 256;
    int s = 0;
    for (int i = 0; i < per; i++) {
        const int idx = tid * per + i;
        if (idx < NN) s += cnt[idx];
    }
    part[tid] = s;
    __syncthreads();
    if (tid == 0) {
        int r = 0;
        for (int i = 0; i < 256; i++) { const int t = part[i]; part[i] = r; r += t; }
        offs[NN] = r;
    }
    __syncthreads();
    int run = part[tid];
    for (int i = 0; i < per; i++) {
        const int idx = tid * per + i;
        if (idx < NN) {
            offs[idx] = run;
            cur[idx]  = run;
            run += cnt[idx];
        }
    }
}

__global__ __launch_bounds__(256) void k_fill(const int* __restrict__ EI,
                                              int* __restrict__ cur,
                                              int* __restrict__ EIDS,
                                              int* __restrict__ DSTS)
{
    const int e = blockIdx.x * 256 + threadIdx.x;
    const int s = EI[e];
    const int pos = atomicAdd(&cur[s], 1);
    EIDS[pos] = e;
    DSTS[pos] = EI[EE + e];
}

// ---------------------------------------------------------------------------
// Kernel 2: MFMA edge MLP, CSR-ordered.  NOW 32 edges/block (EPB=32):
// LDS 48.5 -> ~24.6 KB so occupancy is wave-capped at 4 blocks x 8 waves
// = 32 waves/CU (+33% vs 24).  Same math, at-loop halved (4->2), grid x2.
// ---------------------------------------------------------------------------
__global__ __launch_bounds__(512, 4) void k_edge_mfma(
    const float* __restrict__ EA, const float* __restrict__ CH,
    const float* __restrict__ EW, const int*   __restrict__ EI,
    const int*   __restrict__ EIDS,
    const short* __restrict__ W1b, const float* __restrict__ b1,
    const short* __restrict__ W2b, const float* __restrict__ b2,
    const short* __restrict__ W3b, const float* __restrict__ b3,
    short* __restrict__ XC)
{
    __shared__ __align__(16) short sH2[32 * 256];   // 16 KB; first 4 KB = sIn
    __shared__ __align__(16) short sH1[32 * 128];   //  8 KB
    __shared__ float sCut[32];
    __shared__ int   sEid[32];

    short* sIn = sH2;                               // [32][64] alias
    const int tid = threadIdx.x;                    // 0..511
    const int e0  = blockIdx.x * 32;                // CSR base

    {
        if (tid < 256) {                            // zero-fill sIn (4 KB)
            int4_t z = {0, 0, 0, 0};
            ((int4_t*)sIn)[tid] = z;
        }
        if (tid < 32) sEid[tid] = EIDS[e0 + tid];
    }
    __syncthreads();
    {
        if (tid < 256) {                            // stage edge_attr rows
            const int ee  = tid >> 3;               // 0..31
            const int eid = sEid[ee];
            const float4 v = *(const float4*)(EA + (size_t)eid * RD + (tid & 7) * 4);
            const int k = (tid & 7) * 4;
            short4 sv;
            sv.x = f2b(v.x); sv.y = f2b(v.y); sv.z = f2b(v.z); sv.w = f2b(v.w);
            *(short4*)&sIn[ee * 64 + (k ^ ((ee & 7) << 3))] = sv;
        }
        if (tid < 32) {
            const int e2  = tid;
            const int eid2 = sEid[e2];
            const int s = EI[eid2];
            const int d = EI[EE + eid2];
            const int sw = (e2 & 7) << 3;
            sIn[e2 * 64 + (32 ^ sw)] = f2b(CH[s]);
            sIn[e2 * 64 + (33 ^ sw)] = f2b(CH[d]);
            const float w = EW[eid2];
            sCut[e2] = (w < 5.0f)
                     ? 0.5f * (__cosf(0.62831853071795864769f * w) + 1.0f) : 0.0f;
        }
    }
    __syncthreads();

    const int lane = tid & 63;
    const int wid  = tid >> 6;          // 0..7
    const int l15  = lane & 15;
    const int g    = lane >> 4;
    const int fsw  = l15 << 3;

    // ---- layer 1: 32 edges @ W1 (64->128); wave does ct = wid ----
    {
        short8_t E1[2][2];
#pragma unroll
        for (int at = 0; at < 2; at++) {
            const int row = at * 16 + l15;
            const int x = (row & 7) << 3;
            E1[at][0] = *(const short8_t*)&sIn[row * 64 + ((g * 8) ^ x)];
            E1[at][1] = *(const short8_t*)&sIn[row * 64 + ((32 + g * 8) ^ x)];
        }
        const int ct = wid;
        const float4 b4 = *(const float4*)&b1[ct * 16 + g * 4];
        const short8_t av0 = *(const short8_t*)(W1b + (size_t)((ct * 2 + 0) * 64 + lane) * 8);
        const short8_t av1 = *(const short8_t*)(W1b + (size_t)((ct * 2 + 1) * 64 + lane) * 8);
        const int fcol = ct * 16 + g * 4;
#pragma unroll
        for (int at = 0; at < 2; at++) {
            f32x4_t acc = {b4.x, b4.y, b4.z, b4.w};
            acc = __builtin_amdgcn_mfma_f32_16x16x32_bf16(av0, E1[at][0], acc, 0, 0, 0);
            acc = __builtin_amdgcn_mfma_f32_16x16x32_bf16(av1, E1[at][1], acc, 0, 0, 0);
            const int edge = at * 16 + l15;
            uint2 u;
            u.x = cvt_pk(silu_f(acc[0]), silu_f(acc[1]));
            u.y = cvt_pk(silu_f(acc[2]), silu_f(acc[3]));
            *(uint2*)&sH1[edge * 128 + (fcol ^ fsw)] = u;
        }
    }
    __syncthreads();

    // ---- layer 2: @ W2 (128->256); wave does cts {wid, wid+8} ----
    {
        short8_t E2[2][4];
#pragma unroll
        for (int at = 0; at < 2; at++) {
            const int row = at * 16 + l15;
            const int x = (row & 15) << 3;
#pragma unroll
            for (int kb = 0; kb < 4; kb++)
                E2[at][kb] = *(const short8_t*)&sH1[row * 128 + ((kb * 32 + g * 8) ^ x)];
        }
#pragma unroll
        for (int c = 0; c < 2; c++) {
            const int ct = c * 8 + wid;
            const float4 b4 = *(const float4*)&b2[ct * 16 + g * 4];
            const int fcol = ct * 16 + g * 4;
            f32x4_t acc[2];
#pragma unroll
            for (int at = 0; at < 2; at++) acc[at] = {b4.x, b4.y, b4.z, b4.w};
#pragma unroll
            for (int kb = 0; kb < 4; kb++) {
                const short8_t av = *(const short8_t*)(W2b + (size_t)((ct * 4 + kb) * 64 + lane) * 8);
#pragma unroll
                for (int at = 0; at < 2; at++)
                    acc[at] = __builtin_amdgcn_mfma_f32_16x16x32_bf16(av, E2[at][kb], acc[at], 0, 0, 0);
            }
#pragma unroll
            for (int at = 0; at < 2; at++) {
                const int edge = at * 16 + l15;
                uint2 u;
                u.x = cvt_pk(silu_f(acc[at][0]), silu_f(acc[at][1]));
                u.y = cvt_pk(silu_f(acc[at][2]), silu_f(acc[at][3]));
                *(uint2*)&sH2[edge * 256 + (fcol ^ fsw)] = u;
            }
        }
    }
    __syncthreads();

    // ---- layer 3: @ W3 (256->384); wave does cts {wid, wid+8, wid+16} ----
    {
        short8_t E3[2][8];
#pragma unroll
        for (int at = 0; at < 2; at++) {
            const int row = at * 16 + l15;
            const int x = (row & 15) << 3;
#pragma unroll
            for (int kb = 0; kb < 8; kb++)
                E3[at][kb] = *(const short8_t*)&sH2[row * 256 + ((kb * 32 + g * 8) ^ x)];
        }
        float cut[2];
#pragma unroll
        for (int at = 0; at < 2; at++) cut[at] = sCut[at * 16 + l15];
        for (int c = 0; c < 3; c++) {
            const int ct = c * 8 + wid;
            const float4 b4 = *(const float4*)&b3[ct * 16 + g * 4];
            const int fcol = ct * 16 + g * 4;
            f32x4_t acc[2];
#pragma unroll
            for (int at = 0; at < 2; at++) acc[at] = {b4.x, b4.y, b4.z, b4.w};
#pragma unroll
            for (int kb = 0; kb < 8; kb++) {
                const short8_t av = *(const short8_t*)(W3b + (size_t)((ct * 8 + kb) * 64 + lane) * 8);
#pragma unroll
                for (int at = 0; at < 2; at++)
                    acc[at] = __builtin_amdgcn_mfma_f32_16x16x32_bf16(av, E3[at][kb], acc[at], 0, 0, 0);
            }
#pragma unroll
            for (int at = 0; at < 2; at++) {
                const int edge = at * 16 + l15;
                const float cv = cut[at];
                uint2 u;
                u.x = cvt_pk(silu_f(acc[at][0]) * cv, silu_f(acc[at][1]) * cv);
                u.y = cvt_pk(silu_f(acc[at][2]) * cv, silu_f(acc[at][3]) * cv);
                *(uint2*)&XC[(size_t)(e0 + edge) * 384 + fcol] = u;
            }
        }
    }
}

// ---------------------------------------------------------------------------
// Kernel 2b: node-major gather.  1 node / 128-thread block; p-loop x4.
// ---------------------------------------------------------------------------
__global__ __launch_bounds__(128) void k_gather(
    const short* __restrict__ XC, const short* __restrict__ Y,
    const int* __restrict__ offs, const int* __restrict__ DSTS,
    short* __restrict__ MSGb)
{
    const int h   = threadIdx.x;          // 0..127
    const int n   = blockIdx.x;
    const int beg = offs[n], end = offs[n + 1];

    float m[9];
#pragma unroll
    for (int c = 0; c < 9; c++) m[c] = 0.f;

    int p = beg;
    for (; p + 4 <= end; p += 4) {
        float xv[4][3];
        float yv[4][9];
#pragma unroll
        for (int u = 0; u < 4; u++) {
            const size_t xb = (size_t)(p + u) * 384;
            xv[u][0] = b2f(XC[xb + h]);
            xv[u][1] = b2f(XC[xb + 128 + h]);
            xv[u][2] = b2f(XC[xb + 256 + h]);
            const int yb = DSTS[p + u] * HD + h;
#pragma unroll
            for (int c = 0; c < 9; c++)
                yv[u][c] = b2f(Y[(size_t)c * NH + yb]);
        }
#pragma unroll
        for (int u = 0; u < 4; u++) {
            m[0] = fmaf(xv[u][0], yv[u][0], m[0]);
            m[1] = fmaf(xv[u][1], yv[u][1], m[1]);
            m[2] = fmaf(xv[u][1], yv[u][2], m[2]);
            m[3] = fmaf(xv[u][1], yv[u][3], m[3]);
            m[4] = fmaf(xv[u][2], yv[u][4], m[4]);
            m[5] = fmaf(xv[u][2], yv[u][5], m[5]);
            m[6] = fmaf(xv[u][2], yv[u][6], m[6]);
            m[7] = fmaf(xv[u][2], yv[u][7], m[7]);
            m[8] = fmaf(xv[u][2], yv[u][8], m[8]);
        }
    }
    for (; p < end; ++p) {
        const int dst = DSTS[p];
        const size_t xb = (size_t)p * 384;
        const float x0 = b2f(XC[xb + h]);
        const float x1 = b2f(XC[xb + 128 + h]);
        const float x2 = b2f(XC[xb + 256 + h]);
        const int yb = dst * HD + h;
        m[0] = fmaf(x0, b2f(Y[0 * (size_t)NH + yb]), m[0]);
        m[1] = fmaf(x1, b2f(Y[1 * (size_t)NH + yb]), m[1]);
        m[2] = fmaf(x1, b2f(Y[2 * (size_t)NH + yb]), m[2]);
        m[3] = fmaf(x1, b2f(Y[3 * (size_t)NH + yb]), m[3]);
        m[4] = fmaf(x2, b2f(Y[4 * (size_t)NH + yb]), m[4]);
        m[5] = fmaf(x2, b2f(Y[5 * (size_t)NH + yb]), m[5]);
        m[6] = fmaf(x2, b2f(Y[6 * (size_t)NH + yb]), m[6]);
        m[7] = fmaf(x2, b2f(Y[7 * (size_t)NH + yb]), m[7]);
        m[8] = fmaf(x2, b2f(Y[8 * (size_t)NH + yb]), m[8]);
    }
    const int base = n * HD + h;
#pragma unroll
    for (int c = 0; c < 9; c++) MSGb[(size_t)c * NH + base] = f2b(m[c]);
}

// ---------------------------------------------------------------------------
// Fallback (small ws): fused VALU edge MLP + atomic scatter (fp32 MSG).
// ---------------------------------------------------------------------------
__global__ __launch_bounds__(256) void k_edge_atomic(
    const float* __restrict__ EA, const float* __restrict__ CH,
    const float* __restrict__ EW, const int*   __restrict__ EI,
    const float* __restrict__ W1, const float* __restrict__ b1,
    const float* __restrict__ W2, const float* __restrict__ b2,
    const float* __restrict__ W3, const float* __restrict__ b3,
    const float* __restrict__ Y,  float* __restrict__ MSG)
{
    __shared__ __align__(16) float sInf[32 * 35];
    __shared__ __align__(16) float sH1f[32 * 132];
    __shared__ __align__(16) float sH2f[32 * 260];
    __shared__ __align__(16) float sXcf[32 * 132];
    __shared__ float sCc[32];
    __shared__ int   sS[32], sD[32];

    const int e0  = blockIdx.x * 32;
    const int tid = threadIdx.x;

    {
        const float4 v = ((const float4*)(EA + (size_t)e0 * RD))[tid];
        const int e = tid >> 3;
        const int k = (tid & 7) * 4;
        float* p = sInf + e * 35 + k;
        p[0] = v.x; p[1] = v.y; p[2] = v.z; p[3] = v.w;
    }
    if (tid < 32) {
        const int e = tid;
        const int s = EI[e0 + e];
        const int d = EI[EE + e0 + e];
        sS[e] = s; sD[e] = d;
        sInf[e * 35 + 32] = CH[s];
        sInf[e * 35 + 33] = CH[d];
        const float w = EW[e0 + e];
        sCc[e] = (w < 5.0f) ? 0.5f * (__cosf(0.62831853071795864769f * w) + 1.0f)
                            : 0.0f;
    }
    __syncthreads();

    const int e  = tid & 31;
    const int og = tid >> 5;

    {
        float acc[16];
#pragma unroll
        for (int j = 0; j < 16; j++) acc[j] = b1[og * 16 + j];
        for (int k = 0; k < 34; k++) {
            const float v = sInf[e * 35 + k];
#pragma unroll
            for (int j = 0; j < 16; j++)
                acc[j] = fmaf(v, W1[(og * 16 + j) * 34 + k], acc[j]);
        }
#pragma unroll
        for (int j = 0; j < 16; j++)
            sH1f[e * 132 + og * 16 + j] = silu_f(acc[j]);
    }
    __syncthreads();

    {
        float acc[32];
#pragma unroll
        for (int j = 0; j < 32; j++) acc[j] = b2[og * 32 + j];
        for (int hq = 0; hq < 32; hq++) {
            const float4 v = *(const float4*)&sH1f[e * 132 + hq * 4];
#pragma unroll
            for (int j = 0; j < 32; j++) {
                const float4 w =
                    *(const float4*)&W2[(size_t)(og * 32 + j) * 128 + hq * 4];
                acc[j] = fmaf(v.x, w.x, fmaf(v.y, w.y,
                         fmaf(v.z, w.z, fmaf(v.w, w.w, acc[j]))));
            }
        }
#pragma unroll
        for (int j = 0; j < 32; j++)
            sH2f[e * 260 + og * 32 + j] = silu_f(acc[j]);
    }
    __syncthreads();

    for (int c = 0; c < 3; c++) {
        {
            float acc[16];
#pragma unroll
            for (int j = 0; j < 16; j++) acc[j] = b3[c * 128 + og * 16 + j];
            for (int hq = 0; hq < 64; hq++) {
                const float4 v = *(const float4*)&sH2f[e * 260 + hq * 4];
#pragma unroll
                for (int j = 0; j < 16; j++) {
                    const float4 w = *(const float4*)
                        &W3[(size_t)(c * 128 + og * 16 + j) * 256 + hq * 4];
                    acc[j] = fmaf(v.x, w.x, fmaf(v.y, w.y,
                             fmaf(v.z, w.z, fmaf(v.w, w.w, acc[j]))));
                }
            }
            const float cc = sCc[e];
#pragma unroll
            for (int j = 0; j < 16; j++)
                sXcf[e * 132 + og * 16 + j] = silu_f(acc[j]) * cc;
        }
        __syncthreads();
        {
            const int h  = tid & 127;
            const int eh = tid >> 7;
#pragma unroll 4
            for (int i = 0; i < 16; i++) {
                const int ee = (eh << 4) | i;
                const int s = sS[ee], d = sD[ee];
                const float xv = sXcf[ee * 132 + h];
                const int sb = s * HD + h, db = d * HD + h;
                if (c == 0) {
                    atomicAdd(&MSG[0 * (size_t)NH + sb], xv * Y[0 * (size_t)NH + db]);
                } else if (c == 1) {
#pragma unroll
                    for (int cc2 = 1; cc2 < 4; cc2++)
                        atomicAdd(&MSG[(size_t)cc2 * NH + sb],
                                  xv * Y[(size_t)cc2 * NH + db]);
                } else {
#pragma unroll
                    for (int cc2 = 4; cc2 < 9; cc2++)
                        atomicAdd(&MSG[(size_t)cc2 * NH + sb],
                                  xv * Y[(size_t)cc2 * NH + db]);
                }
            }
        }
        __syncthreads();
    }
}

// ---------------------------------------------------------------------------
static inline size_t align_up(size_t v, size_t a) { return (v + a - 1) & ~(a - 1); }

extern "C" void kernel_launch(void* const* d_in, const int* in_sizes, int n_in,
                              void* d_out, int out_size, void* d_ws, size_t ws_size,
                              hipStream_t stream)
{
    const float* X   = (const float*)d_in[0];
    const float* CH  = (const float*)d_in[1];
    const float* EA  = (const float*)d_in[2];
    const float* EW  = (const float*)d_in[3];
    const float* W1  = (const float*)d_in[4];
    const float* b1  = (const float*)d_in[5];
    const float* W2  = (const float*)d_in[6];
    const float* b2  = (const float*)d_in[7];
    const float* W3  = (const float*)d_in[8];
    const float* b3  = (const float*)d_in[9];
    const float* Wt0 = (const float*)d_in[10];
    const float* Wt1 = (const float*)d_in[11];
    const float* Wt2 = (const float*)d_in[12];
    const float* Wt3 = (const float*)d_in[13];
    const float* Wt4 = (const float*)d_in[14];
    const float* Wt5 = (const float*)d_in[15];
    const int*   EI  = (const int*)d_in[16];
    float* out = (float*)d_out;

    size_t off = 0;
    float* Y    = (float*)((char*)d_ws + off); off = align_up(off + (size_t)9 * NH * 4, 64);
    float* MSG  = (float*)((char*)d_ws + off); off = align_up(off + (size_t)9 * NH * 4, 64);
    short* MSGb = (short*)MSG;   // alias: bf16 MSG planes (fast path)
    int*   cnt  = (int*)((char*)d_ws + off);   off = align_up(off + (size_t)NN * 4, 64);
    int*   cur  = (int*)((char*)d_ws + off);   off = align_up(off + (size_t)NN * 4, 64);
    int*   offs = (int*)((char*)d_ws + off);   off = align_up(off + (size_t)(NN + 1) * 4, 64);
    int*   EIDS = (int*)((char*)d_ws + off);   off = align_up(off + (size_t)EE * 4, 64);
    int*   DSTS = (int*)((char*)d_ws + off);   off = align_up(off + (size_t)EE * 4, 64);
    short* W1b  = (short*)((char*)d_ws + off); off = align_up(off + (size_t)8192 * 2, 64);
    short* W2b  = (short*)((char*)d_ws + off); off = align_up(off + (size_t)32768 * 2, 64);
    short* W3b  = (short*)((char*)d_ws + off); off = align_up(off + (size_t)98304 * 2, 64);
    short* WtPh = (short*)((char*)d_ws + off); off = align_up(off + (size_t)3 * 16384 * 2, 64);
    short* WtPl = (short*)((char*)d_ws + off); off = align_up(off + (size_t)3 * 16384 * 2, 64);
    short* WtFh = (short*)((char*)d_ws + off); off = align_up(off + (size_t)3 * 16384 * 2, 64);
    short* WtFl = (short*)((char*)d_ws + off); off = align_up(off + (size_t)3 * 16384 * 2, 64);
    short* XC   = (short*)((char*)d_ws + off); off = align_up(off + (size_t)EE * 384 * 2, 64);
    short* Ybf  = (short*)((char*)d_ws + off); off = align_up(off + (size_t)9 * NH * 2, 64);
    const size_t need_fast = off;

    hipMemsetAsync(cnt, 0, (size_t)NN * sizeof(int), stream);
    k_wconv<<<1553, 256, 0, stream>>>(W1, W2, W3, Wt0, Wt1, Wt2, Wt3, Wt4, Wt5,
                                      EI, cnt,
                                      W1b, W2b, W3b, WtPh, WtPl, WtFh, WtFl);

    if (ws_size >= need_fast) {
        k_mix_prep<true><<<NN / 16, 512, 73728, stream>>>(X, WtPh, WtPl, Y, Ybf);
        k_scan<<<1, 256, 0, stream>>>(cnt, offs, cur);
        k_fill<<<EE / 256, 256, 0, stream>>>(EI, cur, EIDS, DSTS);
        k_edge_mfma<<<EE / 32, 512, 0, stream>>>(EA, CH, EW, EI, EIDS,
                                                 W1b, b1, W2b, b2, W3b, b3, XC);
        k_gather<<<NN, 128, 0, stream>>>(XC, Ybf, offs, DSTS, MSGb);
        k_mix_fin<short, short><<<NN / 16, 512, 73728, stream>>>(
            X, Ybf, MSGb, WtFh, WtFl, out);
    } else {
        k_mix_prep<false><<<NN / 16, 512, 73728, stream>>>(X, WtPh, WtPl, Y, Ybf);
        hipMemsetAsync(MSG, 0, (size_t)9 * NH * sizeof(float), stream);
        k_edge_atomic<<<EE / 32, 256, 0, stream>>>(EA, CH, EW, EI,
                                                   W1, b1, W2, b2, W3, b3, Y, MSG);
        k_mix_fin<float, float><<<NN / 16, 512, 73728, stream>>>(
            X, Y, MSG, WtFh, WtFl, out);
    }
}

// Round 20
// 309.399 us; speedup vs baseline: 1.0004x; 1.0004x over previous
//
#include <hip/hip_runtime.h>

#define NN  10000
#define HD  128
#define EE  160000
#define RD  32
#define NH  (NN * HD)

typedef __attribute__((ext_vector_type(8))) short short8_t;
typedef __attribute__((ext_vector_type(4))) float f32x4_t;
typedef __attribute__((ext_vector_type(4))) int   int4_t;

// fast silu: v_rcp_f32 (~1ulp) instead of exact-div sequence
__device__ __forceinline__ float silu_f(float z) {
    return z * __builtin_amdgcn_rcpf(1.0f + __expf(-z));
}
__device__ __forceinline__ short f2b(float v) {   // RNE fp32->bf16
    unsigned u = __float_as_uint(v);
    unsigned r = (u + 0x7FFFu + ((u >> 16) & 1u)) >> 16;
    return (short)r;
}
__device__ __forceinline__ float b2f(short s) {
    return __uint_as_float(((unsigned)(unsigned short)s) << 16);
}
// HW packed convert: bits[15:0]=bf16(a), bits[31:16]=bf16(b), RNE.
__device__ __forceinline__ unsigned cvt_pk(float a, float b) {
    unsigned r;
    asm("v_cvt_pk_bf16_f32 %0, %1, %2" : "=v"(r) : "v"(a), "v"(b));
    return r;
}
__device__ __forceinline__ float ldy(const float* p) { return *p; }
__device__ __forceinline__ float ldy(const short* p) { return b2f(*p); }

// ---------------------------------------------------------------------------
// Weight conversion + edge histogram folded into tail blocks (grid 1553).
// ---------------------------------------------------------------------------
__global__ __launch_bounds__(256) void k_wconv(
    const float* __restrict__ W1, const float* __restrict__ W2,
    const float* __restrict__ W3,
    const float* __restrict__ Wt0, const float* __restrict__ Wt1,
    const float* __restrict__ Wt2, const float* __restrict__ Wt3,
    const float* __restrict__ Wt4, const float* __restrict__ Wt5,
    const int* __restrict__ EI,   int* __restrict__ cnt,
    short* __restrict__ W1b, short* __restrict__ W2b, short* __restrict__ W3b,
    short* __restrict__ WtPh, short* __restrict__ WtPl,
    short* __restrict__ WtFh, short* __restrict__ WtFl)
{
    if (blockIdx.x >= 928) {              // histogram tail: 625 blocks
        const int e = (blockIdx.x - 928) * 256 + threadIdx.x;
        atomicAdd(&cnt[EI[e]], 1);
        return;
    }
    const int i = blockIdx.x * 256 + threadIdx.x;
    if (i < 8192) {                       // layer1: ct<8, kb<2, K_in=34
        const int j = i & 7, lane = (i >> 3) & 63;
        const int kb = (i >> 9) & 1, ct = i >> 10;
        const int n = ct * 16 + (lane & 15);
        const int k = kb * 32 + (lane >> 4) * 8 + j;
        W1b[i] = (k < 34) ? f2b(W1[n * 34 + k]) : (short)0;
        return;
    }
    int j2 = i - 8192;
    if (j2 < 32768) {                     // layer2: ct<16, kb<4, K_in=128
        const int j = j2 & 7, lane = (j2 >> 3) & 63;
        const int kb = (j2 >> 9) & 3, ct = j2 >> 11;
        const int n = ct * 16 + (lane & 15);
        const int k = kb * 32 + (lane >> 4) * 8 + j;
        W2b[j2] = f2b(W2[n * 128 + k]);
        return;
    }
    j2 -= 32768;
    if (j2 < 98304) {                     // layer3: ct<24, kb<8, K_in=256
        const int j = j2 & 7, lane = (j2 >> 3) & 63;
        const int kb = (j2 >> 9) & 7, ct = j2 >> 12;
        const int n = ct * 16 + (lane & 15);
        const int k = kb * 32 + (lane >> 4) * 8 + j;
        W3b[j2] = f2b(W3[n * 256 + k]);
        return;
    }
    j2 -= 98304;
    if (j2 < 6 * 16384) {
        const int m = j2 >> 14, idx = j2 & 16383;
        const float* src = (m == 0) ? Wt0 : (m == 1) ? Wt1 : (m == 2) ? Wt2
                         : (m == 3) ? Wt3 : (m == 4) ? Wt4 : Wt5;
        const float w = src[idx];
        const short hi = f2b(w);
        const short lo = f2b(w - b2f(hi));
        if (m < 3) { WtPh[m * 16384 + idx] = hi; WtPl[m * 16384 + idx] = lo; }
        else       { WtFh[(m - 3) * 16384 + idx] = hi; WtFl[(m - 3) * 16384 + idx] = lo; }
    }
}

// ---------------------------------------------------------------------------
// k_mix_prep<YBF16>: decompose X, channel-mix with WtP (hi/lo split).
// ---------------------------------------------------------------------------
template <bool YBF16>
__global__ __launch_bounds__(512, 4) void k_mix_prep(
    const float* __restrict__ X,
    const short* __restrict__ Wh, const short* __restrict__ Wl,
    float* __restrict__ Yf, short* __restrict__ ybf)
{
    extern __shared__ __align__(16) char smem[];   // 73728 B
    short* sBh = (short*)smem;
    short* sBl = sBh + 144 * 128;
    float* sC  = (float*)smem;

    const int tid = threadIdx.x;
    const int n0  = blockIdx.x * 16;

#pragma unroll 2
    for (int i = 0; i < 4; i++) {
        const int p  = i * 512 + tid;
        const int nl = p >> 7, h = p & 127;
        const float* t = X + ((size_t)((n0 + nl) * HD + h)) * 9;
        float T[9];
#pragma unroll
        for (int q = 0; q < 9; q++) T[q] = t[q];
        float nrm = 0.f;
#pragma unroll
        for (int q = 0; q < 9; q++) nrm = fmaf(T[q], T[q], nrm);
        const float inv = 1.0f / (nrm + 1.0f);
#pragma unroll
        for (int q = 0; q < 9; q++) T[q] *= inv;
        const float I = (T[0] + T[4] + T[8]) * (1.0f / 3.0f);
        float dec[9];
        dec[0] = I;
        dec[1] = 0.5f * (T[7] - T[5]);
        dec[2] = 0.5f * (T[2] - T[6]);
        dec[3] = 0.5f * (T[3] - T[1]);
        dec[4] = T[0] - I;
        dec[5] = 0.5f * (T[1] + T[3]);
        dec[6] = 0.5f * (T[2] + T[6]);
        dec[7] = T[4] - I;
        dec[8] = 0.5f * (T[5] + T[7]);
        const int sw = (nl & 7) << 3;
        const int hx = h ^ sw;
#pragma unroll
        for (int c = 0; c < 9; c++) {
            const float v  = dec[c];
            const short hi = f2b(v);
            const short lo = f2b(v - b2f(hi));
            const int idx = (c * 16 + nl) * 128 + hx;
            sBh[idx] = hi;
            sBl[idx] = lo;
        }
    }
    __syncthreads();

    const int lane = tid & 63, wid = tid >> 6;
    const int l15 = lane & 15, g = lane >> 4;
    f32x4_t acc[9];
#pragma unroll
    for (int c = 0; c < 9; c++) acc[c] = {0.f, 0.f, 0.f, 0.f};

    const int bsw = (l15 & 7) << 3;
    const int o   = wid * 16 + l15;
#pragma unroll
    for (int k = 0; k < 4; k++) {
        const int k0  = k * 32 + g * 8;
        const int ksw = k0 ^ bsw;
#pragma unroll
        for (int w = 0; w < 3; w++) {
            const size_t aoff = (size_t)w * 16384 + (size_t)o * 128 + k0;
            const short8_t Ah = *(const short8_t*)(Wh + aoff);
            const short8_t Al = *(const short8_t*)(Wl + aoff);
            const int ct0 = (w == 0) ? 0 : (w == 1 ? 1 : 4);
            const int ctn = (w == 0) ? 1 : (w == 1 ? 3 : 5);
            for (int cc = 0; cc < ctn; cc++) {
                const int ct = ct0 + cc;
                const int boff = (ct * 16 + l15) * 128 + ksw;
                const short8_t Bh = *(const short8_t*)&sBh[boff];
                const short8_t Bl = *(const short8_t*)&sBl[boff];
                acc[ct] = __builtin_amdgcn_mfma_f32_16x16x32_bf16(Al, Bh, acc[ct], 0, 0, 0);
                acc[ct] = __builtin_amdgcn_mfma_f32_16x16x32_bf16(Ah, Bl, acc[ct], 0, 0, 0);
                acc[ct] = __builtin_amdgcn_mfma_f32_16x16x32_bf16(Ah, Bh, acc[ct], 0, 0, 0);
            }
        }
    }
    __syncthreads();

    const int csw = (l15 & 7) << 2;
    {
        const int o0 = wid * 16 + g * 4;
#pragma unroll
        for (int ct = 0; ct < 9; ct++)
            *(f32x4_t*)&sC[(ct * 16 + l15) * 128 + (o0 ^ csw)] = acc[ct];
    }
    __syncthreads();

    for (int i = tid; i < 144 * 32; i += 512) {
        const int row = i >> 5, q = i & 31;
        const int c = row >> 4, nl = row & 15;
        const int sw = (nl & 7) << 2;
        const f32x4_t v = *(const f32x4_t*)&sC[row * 128 + ((q * 4) ^ sw)];
        const size_t oo = (size_t)c * NH + (size_t)(n0 + nl) * HD + q * 4;
        if constexpr (YBF16) {
            uint2 u;
            u.x = cvt_pk(v[0], v[1]);
            u.y = cvt_pk(v[2], v[3]);
            *(uint2*)&ybf[oo] = u;
        } else {
            *(f32x4_t*)&Yf[oo] = v;
        }
    }
}

// ---------------------------------------------------------------------------
// k_mix_fin<YT, MT>: M = msg*Y + Y*msg; decompose/normalize; mix WtF; out.
// ---------------------------------------------------------------------------
template <typename YT, typename MT>
__global__ __launch_bounds__(512, 4) void k_mix_fin(
    const float* __restrict__ X,
    const YT* __restrict__ Yp, const MT* __restrict__ Mp,
    const short* __restrict__ Wh, const short* __restrict__ Wl,
    float* __restrict__ outp)
{
    extern __shared__ __align__(16) char smem[];   // 73728 B
    short* sBh = (short*)smem;
    short* sBl = sBh + 144 * 128;
    float* sC  = (float*)smem;

    const int tid = threadIdx.x;
    const int n0  = blockIdx.x * 16;

#pragma unroll 2
    for (int i = 0; i < 4; i++) {
        const int p  = i * 512 + tid;
        const int nl = p >> 7, h = p & 127;
        const int basep = (n0 + nl) * HD + h;
        float yv[9], mv[9];
#pragma unroll
        for (int c = 0; c < 9; c++) {
            yv[c] = ldy(Yp + (size_t)c * NH + basep);
            mv[c] = ldy(Mp + (size_t)c * NH + basep);
        }
        float Yt[9], G[9];
        {
            const float I = yv[0], a0 = yv[1], a1 = yv[2], a2 = yv[3];
            const float s00 = yv[4], s01 = yv[5], s02 = yv[6], s11 = yv[7], s12 = yv[8];
            const float s22 = -s00 - s11;
            Yt[0] = I + s00; Yt[1] = s01 - a2; Yt[2] = s02 + a1;
            Yt[3] = s01 + a2; Yt[4] = I + s11; Yt[5] = s12 - a0;
            Yt[6] = s02 - a1; Yt[7] = s12 + a0; Yt[8] = I + s22;
        }
        {
            const float I = mv[0], a0 = mv[1], a1 = mv[2], a2 = mv[3];
            const float s00 = mv[4], s01 = mv[5], s02 = mv[6], s11 = mv[7], s12 = mv[8];
            const float s22 = -s00 - s11;
            G[0] = I + s00; G[1] = s01 - a2; G[2] = s02 + a1;
            G[3] = s01 + a2; G[4] = I + s11; G[5] = s12 - a0;
            G[6] = s02 - a1; G[7] = s12 + a0; G[8] = I + s22;
        }
        float M[9];
#pragma unroll
        for (int r = 0; r < 3; r++)
#pragma unroll
            for (int cc = 0; cc < 3; cc++) {
                float a = 0.f;
#pragma unroll
                for (int k = 0; k < 3; k++)
                    a += G[r * 3 + k] * Yt[k * 3 + cc]
                       + Yt[r * 3 + k] * G[k * 3 + cc];
                M[r * 3 + cc] = a;
            }
        const float I2 = (M[0] + M[4] + M[8]) * (1.0f / 3.0f);
        const float a0 = 0.5f * (M[7] - M[5]);
        const float a1 = 0.5f * (M[2] - M[6]);
        const float a2 = 0.5f * (M[3] - M[1]);
        const float s00 = M[0] - I2, s11 = M[4] - I2;
        const float s01 = 0.5f * (M[1] + M[3]);
        const float s02 = 0.5f * (M[2] + M[6]);
        const float s12 = 0.5f * (M[5] + M[7]);
        const float s22 = -s00 - s11;
        const float nrm = 2.f * (a0 * a0 + a1 * a1 + a2 * a2)
                        + (s00 * s00 + s11 * s11 + s22 * s22)
                        + 2.f * (s01 * s01 + s02 * s02 + s12 * s12)
                        + 3.f * I2 * I2;
        const float inv = 1.0f / (nrm + 1.0f);
        float dec[9];
        dec[0] = I2 * inv;  dec[1] = a0 * inv;  dec[2] = a1 * inv;
        dec[3] = a2 * inv;  dec[4] = s00 * inv; dec[5] = s01 * inv;
        dec[6] = s02 * inv; dec[7] = s11 * inv; dec[8] = s12 * inv;

        const int sw = (nl & 7) << 3;
        const int hx = h ^ sw;
#pragma unroll
        for (int c = 0; c < 9; c++) {
            const float v  = dec[c];
            const short hi = f2b(v);
            const short lo = f2b(v - b2f(hi));
            const int idx = (c * 16 + nl) * 128 + hx;
            sBh[idx] = hi;
            sBl[idx] = lo;
        }
    }
    __syncthreads();

    const int lane = tid & 63, wid = tid >> 6;
    const int l15 = lane & 15, g = lane >> 4;
    f32x4_t acc[9];
#pragma unroll
    for (int c = 0; c < 9; c++) acc[c] = {0.f, 0.f, 0.f, 0.f};

    const int bsw = (l15 & 7) << 3;
    const int o   = wid * 16 + l15;
#pragma unroll
    for (int k = 0; k < 4; k++) {
        const int k0  = k * 32 + g * 8;
        const int ksw = k0 ^ bsw;
#pragma unroll
        for (int w = 0; w < 3; w++) {
            const size_t aoff = (size_t)w * 16384 + (size_t)o * 128 + k0;
            const short8_t Ah = *(const short8_t*)(Wh + aoff);
            const short8_t Al = *(const short8_t*)(Wl + aoff);
            const int ct0 = (w == 0) ? 0 : (w == 1 ? 1 : 4);
            const int ctn = (w == 0) ? 1 : (w == 1 ? 3 : 5);
            for (int cc = 0; cc < ctn; cc++) {
                const int ct = ct0 + cc;
                const int boff = (ct * 16 + l15) * 128 + ksw;
                const short8_t Bh = *(const short8_t*)&sBh[boff];
                const short8_t Bl = *(const short8_t*)&sBl[boff];
                acc[ct] = __builtin_amdgcn_mfma_f32_16x16x32_bf16(Al, Bh, acc[ct], 0, 0, 0);
                acc[ct] = __builtin_amdgcn_mfma_f32_16x16x32_bf16(Ah, Bl, acc[ct], 0, 0, 0);
                acc[ct] = __builtin_amdgcn_mfma_f32_16x16x32_bf16(Ah, Bh, acc[ct], 0, 0, 0);
            }
        }
    }
    __syncthreads();

    const int csw = (l15 & 7) << 2;
    {
        const int o0 = wid * 16 + g * 4;
#pragma unroll
        for (int ct = 0; ct < 9; ct++)
            *(f32x4_t*)&sC[(ct * 16 + l15) * 128 + (o0 ^ csw)] = acc[ct];
    }
    __syncthreads();

#pragma unroll 2
    for (int i = 0; i < 4; i++) {
        const int p  = i * 512 + tid;
        const int nl = p >> 7, oo = p & 127;
        const int sw = (nl & 7) << 2;
        const int ox = oo ^ sw;
        float a9[9];
#pragma unroll
        for (int c = 0; c < 9; c++) a9[c] = sC[(c * 16 + nl) * 128 + ox];
        float D[9];
        {
            const float I = a9[0], a0 = a9[1], a1 = a9[2], a2 = a9[3];
            const float s00 = a9[4], s01 = a9[5], s02 = a9[6];
            const float s11 = a9[7], s12 = a9[8];
            const float s22 = -s00 - s11;
            D[0] = I + s00; D[1] = s01 - a2; D[2] = s02 + a1;
            D[3] = s01 + a2; D[4] = I + s11; D[5] = s12 - a0;
            D[6] = s02 - a1; D[7] = s12 + a0; D[8] = I + s22;
        }
        const size_t xbase = ((size_t)((n0 + nl) * HD + oo)) * 9;
        float T[9];
#pragma unroll
        for (int q = 0; q < 9; q++) T[q] = X[xbase + q];
        float nrm = 0.f;
#pragma unroll
        for (int q = 0; q < 9; q++) nrm = fmaf(T[q], T[q], nrm);
        const float inv = 1.0f / (nrm + 1.0f);
        float* op = outp + xbase;
#pragma unroll
        for (int r = 0; r < 3; r++)
#pragma unroll
            for (int cc = 0; cc < 3; cc++) {
                float dd2 = 0.f;
#pragma unroll
                for (int k = 0; k < 3; k++)
                    dd2 = fmaf(D[r * 3 + k], D[k * 3 + cc], dd2);
                op[r * 3 + cc] = T[r * 3 + cc] * inv + D[r * 3 + cc] + dd2;
            }
    }
}

// ---------------------------------------------------------------------------
// CSR scan + fill.
// ---------------------------------------------------------------------------
__global__ __launch_bounds__(256) void k_scan(const int* __restrict__ cnt,
                                              int* __restrict__ offs,
                                              int* __restrict__ cur)
{
    __shared__ int part[256];
    const int tid = threadIdx.x;
    const int per = (NN + 255) / 256;
    int s = 0;
    for (int i = 0; i < per; i++) {
        const int idx = tid * per + i;
        if (idx < NN) s += cnt[idx];
    }
    part[tid] = s;
    __syncthreads();
    if (tid == 0) {
        int r = 0;
        for (int i = 0; i < 256; i++) { const int t = part[i]; part[i] = r; r += t; }
        offs[NN] = r;
    }
    __syncthreads();
    int run = part[tid];
    for (int i = 0; i < per; i++) {
        const int idx = tid * per + i;
        if (idx < NN) {
            offs[idx] = run;
            cur[idx]  = run;
            run += cnt[idx];
        }
    }
}

__global__ __launch_bounds__(256) void k_fill(const int* __restrict__ EI,
                                              int* __restrict__ cur,
                                              int* __restrict__ EIDS,
                                              int* __restrict__ DSTS)
{
    const int e = blockIdx.x * 256 + threadIdx.x;
    const int s = EI[e];
    const int pos = atomicAdd(&cur[s], 1);
    EIDS[pos] = e;
    DSTS[pos] = EI[EE + e];
}

// ---------------------------------------------------------------------------
// Kernel 2: MFMA edge MLP, CSR-ordered.  NOW 32 edges/block (EPB=32):
// LDS 48.5 -> ~24.6 KB so occupancy is wave-capped at 4 blocks x 8 waves
// = 32 waves/CU (+33% vs 24).  Same math, at-loop halved (4->2), grid x2.
// ---------------------------------------------------------------------------
__global__ __launch_bounds__(512, 4) void k_edge_mfma(
    const float* __restrict__ EA, const float* __restrict__ CH,
    const float* __restrict__ EW, const int*   __restrict__ EI,
    const int*   __restrict__ EIDS,
    const short* __restrict__ W1b, const float* __restrict__ b1,
    const short* __restrict__ W2b, const float* __restrict__ b2,
    const short* __restrict__ W3b, const float* __restrict__ b3,
    short* __restrict__ XC)
{
    __shared__ __align__(16) short sH2[32 * 256];   // 16 KB; first 4 KB = sIn
    __shared__ __align__(16) short sH1[32 * 128];   //  8 KB
    __shared__ float sCut[32];
    __shared__ int   sEid[32];

    short* sIn = sH2;                               // [32][64] alias
    const int tid = threadIdx.x;                    // 0..511
    const int e0  = blockIdx.x * 32;                // CSR base

    {
        if (tid < 256) {                            // zero-fill sIn (4 KB)
            int4_t z = {0, 0, 0, 0};
            ((int4_t*)sIn)[tid] = z;
        }
        if (tid < 32) sEid[tid] = EIDS[e0 + tid];
    }
    __syncthreads();
    {
        if (tid < 256) {                            // stage edge_attr rows
            const int ee  = tid >> 3;               // 0..31
            const int eid = sEid[ee];
            const float4 v = *(const float4*)(EA + (size_t)eid * RD + (tid & 7) * 4);
            const int k = (tid & 7) * 4;
            short4 sv;
            sv.x = f2b(v.x); sv.y = f2b(v.y); sv.z = f2b(v.z); sv.w = f2b(v.w);
            *(short4*)&sIn[ee * 64 + (k ^ ((ee & 7) << 3))] = sv;
        }
        if (tid < 32) {
            const int e2  = tid;
            const int eid2 = sEid[e2];
            const int s = EI[eid2];
            const int d = EI[EE + eid2];
            const int sw = (e2 & 7) << 3;
            sIn[e2 * 64 + (32 ^ sw)] = f2b(CH[s]);
            sIn[e2 * 64 + (33 ^ sw)] = f2b(CH[d]);
            const float w = EW[eid2];
            sCut[e2] = (w < 5.0f)
                     ? 0.5f * (__cosf(0.62831853071795864769f * w) + 1.0f) : 0.0f;
        }
    }
    __syncthreads();

    const int lane = tid & 63;
    const int wid  = tid >> 6;          // 0..7
    const int l15  = lane & 15;
    const int g    = lane >> 4;
    const int fsw  = l15 << 3;

    // ---- layer 1: 32 edges @ W1 (64->128); wave does ct = wid ----
    {
        short8_t E1[2][2];
#pragma unroll
        for (int at = 0; at < 2; at++) {
            const int row = at * 16 + l15;
            const int x = (row & 7) << 3;
            E1[at][0] = *(const short8_t*)&sIn[row * 64 + ((g * 8) ^ x)];
            E1[at][1] = *(const short8_t*)&sIn[row * 64 + ((32 + g * 8) ^ x)];
        }
        const int ct = wid;
        const float4 b4 = *(const float4*)&b1[ct * 16 + g * 4];
        const short8_t av0 = *(const short8_t*)(W1b + (size_t)((ct * 2 + 0) * 64 + lane) * 8);
        const short8_t av1 = *(const short8_t*)(W1b + (size_t)((ct * 2 + 1) * 64 + lane) * 8);
        const int fcol = ct * 16 + g * 4;
#pragma unroll
        for (int at = 0; at < 2; at++) {
            f32x4_t acc = {b4.x, b4.y, b4.z, b4.w};
            acc = __builtin_amdgcn_mfma_f32_16x16x32_bf16(av0, E1[at][0], acc, 0, 0, 0);
            acc = __builtin_amdgcn_mfma_f32_16x16x32_bf16(av1, E1[at][1], acc, 0, 0, 0);
            const int edge = at * 16 + l15;
            uint2 u;
            u.x = cvt_pk(silu_f(acc[0]), silu_f(acc[1]));
            u.y = cvt_pk(silu_f(acc[2]), silu_f(acc[3]));
            *(uint2*)&sH1[edge * 128 + (fcol ^ fsw)] = u;
        }
    }
    __syncthreads();

    // ---- layer 2: @ W2 (128->256); wave does cts {wid, wid+8} ----
    {
        short8_t E2[2][4];
#pragma unroll
        for (int at = 0; at < 2; at++) {
            const int row = at * 16 + l15;
            const int x = (row & 15) << 3;
#pragma unroll
            for (int kb = 0; kb < 4; kb++)
                E2[at][kb] = *(const short8_t*)&sH1[row * 128 + ((kb * 32 + g * 8) ^ x)];
        }
#pragma unroll
        for (int c = 0; c < 2; c++) {
            const int ct = c * 8 + wid;
            const float4 b4 = *(const float4*)&b2[ct * 16 + g * 4];
            const int fcol = ct * 16 + g * 4;
            f32x4_t acc[2];
#pragma unroll
            for (int at = 0; at < 2; at++) acc[at] = {b4.x, b4.y, b4.z, b4.w};
#pragma unroll
            for (int kb = 0; kb < 4; kb++) {
                const short8_t av = *(const short8_t*)(W2b + (size_t)((ct * 4 + kb) * 64 + lane) * 8);
#pragma unroll
                for (int at = 0; at < 2; at++)
                    acc[at] = __builtin_amdgcn_mfma_f32_16x16x32_bf16(av, E2[at][kb], acc[at], 0, 0, 0);
            }
#pragma unroll
            for (int at = 0; at < 2; at++) {
                const int edge = at * 16 + l15;
                uint2 u;
                u.x = cvt_pk(silu_f(acc[at][0]), silu_f(acc[at][1]));
                u.y = cvt_pk(silu_f(acc[at][2]), silu_f(acc[at][3]));
                *(uint2*)&sH2[edge * 256 + (fcol ^ fsw)] = u;
            }
        }
    }
    __syncthreads();

    // ---- layer 3: @ W3 (256->384); wave does cts {wid, wid+8, wid+16} ----
    {
        short8_t E3[2][8];
#pragma unroll
        for (int at = 0; at < 2; at++) {
            const int row = at * 16 + l15;
            const int x = (row & 15) << 3;
#pragma unroll
            for (int kb = 0; kb < 8; kb++)
                E3[at][kb] = *(const short8_t*)&sH2[row * 256 + ((kb * 32 + g * 8) ^ x)];
        }
        float cut[2];
#pragma unroll
        for (int at = 0; at < 2; at++) cut[at] = sCut[at * 16 + l15];
        for (int c = 0; c < 3; c++) {
            const int ct = c * 8 + wid;
            const float4 b4 = *(const float4*)&b3[ct * 16 + g * 4];
            const int fcol = ct * 16 + g * 4;
            f32x4_t acc[2];
#pragma unroll
            for (int at = 0; at < 2; at++) acc[at] = {b4.x, b4.y, b4.z, b4.w};
#pragma unroll
            for (int kb = 0; kb < 8; kb++) {
                const short8_t av = *(const short8_t*)(W3b + (size_t)((ct * 8 + kb) * 64 + lane) * 8);
#pragma unroll
                for (int at = 0; at < 2; at++)
                    acc[at] = __builtin_amdgcn_mfma_f32_16x16x32_bf16(av, E3[at][kb], acc[at], 0, 0, 0);
            }
#pragma unroll
            for (int at = 0; at < 2; at++) {
                const int edge = at * 16 + l15;
                const float cv = cut[at];
                uint2 u;
                u.x = cvt_pk(silu_f(acc[at][0]) * cv, silu_f(acc[at][1]) * cv);
                u.y = cvt_pk(silu_f(acc[at][2]) * cv, silu_f(acc[at][3]) * cv);
                *(uint2*)&XC[(size_t)(e0 + edge) * 384 + fcol] = u;
            }
        }
    }
}

// ---------------------------------------------------------------------------
// Kernel 2b: node-major gather.  1 node / 128-thread block; p-loop x4.
// ---------------------------------------------------------------------------
__global__ __launch_bounds__(128) void k_gather(
    const short* __restrict__ XC, const short* __restrict__ Y,
    const int* __restrict__ offs, const int* __restrict__ DSTS,
    short* __restrict__ MSGb)
{
    const int h   = threadIdx.x;          // 0..127
    const int n   = blockIdx.x;
    const int beg = offs[n], end = offs[n + 1];

    float m[9];
#pragma unroll
    for (int c = 0; c < 9; c++) m[c] = 0.f;

    int p = beg;
    for (; p + 4 <= end; p += 4) {
        float xv[4][3];
        float yv[4][9];
#pragma unroll
        for (int u = 0; u < 4; u++) {
            const size_t xb = (size_t)(p + u) * 384;
            xv[u][0] = b2f(XC[xb + h]);
            xv[u][1] = b2f(XC[xb + 128 + h]);
            xv[u][2] = b2f(XC[xb + 256 + h]);
            const int yb = DSTS[p + u] * HD + h;
#pragma unroll
            for (int c = 0; c < 9; c++)
                yv[u][c] = b2f(Y[(size_t)c * NH + yb]);
        }
#pragma unroll
        for (int u = 0; u < 4; u++) {
            m[0] = fmaf(xv[u][0], yv[u][0], m[0]);
            m[1] = fmaf(xv[u][1], yv[u][1], m[1]);
            m[2] = fmaf(xv[u][1], yv[u][2], m[2]);
            m[3] = fmaf(xv[u][1], yv[u][3], m[3]);
            m[4] = fmaf(xv[u][2], yv[u][4], m[4]);
            m[5] = fmaf(xv[u][2], yv[u][5], m[5]);
            m[6] = fmaf(xv[u][2], yv[u][6], m[6]);
            m[7] = fmaf(xv[u][2], yv[u][7], m[7]);
            m[8] = fmaf(xv[u][2], yv[u][8], m[8]);
        }
    }
    for (; p < end; ++p) {
        const int dst = DSTS[p];
        const size_t xb = (size_t)p * 384;
        const float x0 = b2f(XC[xb + h]);
        const float x1 = b2f(XC[xb + 128 + h]);
        const float x2 = b2f(XC[xb + 256 + h]);
        const int yb = dst * HD + h;
        m[0] = fmaf(x0, b2f(Y[0 * (size_t)NH + yb]), m[0]);
        m[1] = fmaf(x1, b2f(Y[1 * (size_t)NH + yb]), m[1]);
        m[2] = fmaf(x1, b2f(Y[2 * (size_t)NH + yb]), m[2]);
        m[3] = fmaf(x1, b2f(Y[3 * (size_t)NH + yb]), m[3]);
        m[4] = fmaf(x2, b2f(Y[4 * (size_t)NH + yb]), m[4]);
        m[5] = fmaf(x2, b2f(Y[5 * (size_t)NH + yb]), m[5]);
        m[6] = fmaf(x2, b2f(Y[6 * (size_t)NH + yb]), m[6]);
        m[7] = fmaf(x2, b2f(Y[7 * (size_t)NH + yb]), m[7]);
        m[8] = fmaf(x2, b2f(Y[8 * (size_t)NH + yb]), m[8]);
    }
    const int base = n * HD + h;
#pragma unroll
    for (int c = 0; c < 9; c++) MSGb[(size_t)c * NH + base] = f2b(m[c]);
}

// ---------------------------------------------------------------------------
// Fallback (small ws): fused VALU edge MLP + atomic scatter (fp32 MSG).
// ---------------------------------------------------------------------------
__global__ __launch_bounds__(256) void k_edge_atomic(
    const float* __restrict__ EA, const float* __restrict__ CH,
    const float* __restrict__ EW, const int*   __restrict__ EI,
    const float* __restrict__ W1, const float* __restrict__ b1,
    const float* __restrict__ W2, const float* __restrict__ b2,
    const float* __restrict__ W3, const float* __restrict__ b3,
    const float* __restrict__ Y,  float* __restrict__ MSG)
{
    __shared__ __align__(16) float sInf[32 * 35];
    __shared__ __align__(16) float sH1f[32 * 132];
    __shared__ __align__(16) float sH2f[32 * 260];
    __shared__ __align__(16) float sXcf[32 * 132];
    __shared__ float sCc[32];
    __shared__ int   sS[32], sD[32];

    const int e0  = blockIdx.x * 32;
    const int tid = threadIdx.x;

    {
        const float4 v = ((const float4*)(EA + (size_t)e0 * RD))[tid];
        const int e = tid >> 3;
        const int k = (tid & 7) * 4;
        float* p = sInf + e * 35 + k;
        p[0] = v.x; p[1] = v.y; p[2] = v.z; p[3] = v.w;
    }
    if (tid < 32) {
        const int e = tid;
        const int s = EI[e0 + e];
        const int d = EI[EE + e0 + e];
        sS[e] = s; sD[e] = d;
        sInf[e * 35 + 32] = CH[s];
        sInf[e * 35 + 33] = CH[d];
        const float w = EW[e0 + e];
        sCc[e] = (w < 5.0f) ? 0.5f * (__cosf(0.62831853071795864769f * w) + 1.0f)
                            : 0.0f;
    }
    __syncthreads();

    const int e  = tid & 31;
    const int og = tid >> 5;

    {
        float acc[16];
#pragma unroll
        for (int j = 0; j < 16; j++) acc[j] = b1[og * 16 + j];
        for (int k = 0; k < 34; k++) {
            const float v = sInf[e * 35 + k];
#pragma unroll
            for (int j = 0; j < 16; j++)
                acc[j] = fmaf(v, W1[(og * 16 + j) * 34 + k], acc[j]);
        }
#pragma unroll
        for (int j = 0; j < 16; j++)
            sH1f[e * 132 + og * 16 + j] = silu_f(acc[j]);
    }
    __syncthreads();

    {
        float acc[32];
#pragma unroll
        for (int j = 0; j < 32; j++) acc[j] = b2[og * 32 + j];
        for (int hq = 0; hq < 32; hq++) {
            const float4 v = *(const float4*)&sH1f[e * 132 + hq * 4];
#pragma unroll
            for (int j = 0; j < 32; j++) {
                const float4 w =
                    *(const float4*)&W2[(size_t)(og * 32 + j) * 128 + hq * 4];
                acc[j] = fmaf(v.x, w.x, fmaf(v.y, w.y,
                         fmaf(v.z, w.z, fmaf(v.w, w.w, acc[j]))));
            }
        }
#pragma unroll
        for (int j = 0; j < 32; j++)
            sH2f[e * 260 + og * 32 + j] = silu_f(acc[j]);
    }
    __syncthreads();

    for (int c = 0; c < 3; c++) {
        {
            float acc[16];
#pragma unroll
            for (int j = 0; j < 16; j++) acc[j] = b3[c * 128 + og * 16 + j];
            for (int hq = 0; hq < 64; hq++) {
                const float4 v = *(const float4*)&sH2f[e * 260 + hq * 4];
#pragma unroll
                for (int j = 0; j < 16; j++) {
                    const float4 w = *(const float4*)
                        &W3[(size_t)(c * 128 + og * 16 + j) * 256 + hq * 4];
                    acc[j] = fmaf(v.x, w.x, fmaf(v.y, w.y,
                             fmaf(v.z, w.z, fmaf(v.w, w.w, acc[j]))));
                }
            }
            const float cc = sCc[e];
#pragma unroll
            for (int j = 0; j < 16; j++)
                sXcf[e * 132 + og * 16 + j] = silu_f(acc[j]) * cc;
        }
        __syncthreads();
        {
            const int h  = tid & 127;
            const int eh = tid >> 7;
#pragma unroll 4
            for (int i = 0; i < 16; i++) {
                const int ee = (eh << 4) | i;
                const int s = sS[ee], d = sD[ee];
                const float xv = sXcf[ee * 132 + h];
                const int sb = s * HD + h, db = d * HD + h;
                if (c == 0) {
                    atomicAdd(&MSG[0 * (size_t)NH + sb], xv * Y[0 * (size_t)NH + db]);
                } else if (c == 1) {
#pragma unroll
                    for (int cc2 = 1; cc2 < 4; cc2++)
                        atomicAdd(&MSG[(size_t)cc2 * NH + sb],
                                  xv * Y[(size_t)cc2 * NH + db]);
                } else {
#pragma unroll
                    for (int cc2 = 4; cc2 < 9; cc2++)
                        atomicAdd(&MSG[(size_t)cc2 * NH + sb],
                                  xv * Y[(size_t)cc2 * NH + db]);
                }
            }
        }
        __syncthreads();
    }
}

// ---------------------------------------------------------------------------
static inline size_t align_up(size_t v, size_t a) { return (v + a - 1) & ~(a - 1); }

extern "C" void kernel_launch(void* const* d_in, const int* in_sizes, int n_in,
                              void* d_out, int out_size, void* d_ws, size_t ws_size,
                              hipStream_t stream)
{
    const float* X   = (const float*)d_in[0];
    const float* CH  = (const float*)d_in[1];
    const float* EA  = (const float*)d_in[2];
    const float* EW  = (const float*)d_in[3];
    const float* W1  = (const float*)d_in[4];
    const float* b1  = (const float*)d_in[5];
    const float* W2  = (const float*)d_in[6];
    const float* b2  = (const float*)d_in[7];
    const float* W3  = (const float*)d_in[8];
    const float* b3  = (const float*)d_in[9];
    const float* Wt0 = (const float*)d_in[10];
    const float* Wt1 = (const float*)d_in[11];
    const float* Wt2 = (const float*)d_in[12];
    const float* Wt3 = (const float*)d_in[13];
    const float* Wt4 = (const float*)d_in[14];
    const float* Wt5 = (const float*)d_in[15];
    const int*   EI  = (const int*)d_in[16];
    float* out = (float*)d_out;

    size_t off = 0;
    float* Y    = (float*)((char*)d_ws + off); off = align_up(off + (size_t)9 * NH * 4, 64);
    float* MSG  = (float*)((char*)d_ws + off); off = align_up(off + (size_t)9 * NH * 4, 64);
    short* MSGb = (short*)MSG;   // alias: bf16 MSG planes (fast path)
    int*   cnt  = (int*)((char*)d_ws + off);   off = align_up(off + (size_t)NN * 4, 64);
    int*   cur  = (int*)((char*)d_ws + off);   off = align_up(off + (size_t)NN * 4, 64);
    int*   offs = (int*)((char*)d_ws + off);   off = align_up(off + (size_t)(NN + 1) * 4, 64);
    int*   EIDS = (int*)((char*)d_ws + off);   off = align_up(off + (size_t)EE * 4, 64);
    int*   DSTS = (int*)((char*)d_ws + off);   off = align_up(off + (size_t)EE * 4, 64);
    short* W1b  = (short*)((char*)d_ws + off); off = align_up(off + (size_t)8192 * 2, 64);
    short* W2b  = (short*)((char*)d_ws + off); off = align_up(off + (size_t)32768 * 2, 64);
    short* W3b  = (short*)((char*)d_ws + off); off = align_up(off + (size_t)98304 * 2, 64);
    short* WtPh = (short*)((char*)d_ws + off); off = align_up(off + (size_t)3 * 16384 * 2, 64);
    short* WtPl = (short*)((char*)d_ws + off); off = align_up(off + (size_t)3 * 16384 * 2, 64);
    short* WtFh = (short*)((char*)d_ws + off); off = align_up(off + (size_t)3 * 16384 * 2, 64);
    short* WtFl = (short*)((char*)d_ws + off); off = align_up(off + (size_t)3 * 16384 * 2, 64);
    short* XC   = (short*)((char*)d_ws + off); off = align_up(off + (size_t)EE * 384 * 2, 64);
    short* Ybf  = (short*)((char*)d_ws + off); off = align_up(off + (size_t)9 * NH * 2, 64);
    const size_t need_fast = off;

    hipMemsetAsync(cnt, 0, (size_t)NN * sizeof(int), stream);
    k_wconv<<<1553, 256, 0, stream>>>(W1, W2, W3, Wt0, Wt1, Wt2, Wt3, Wt4, Wt5,
                                      EI, cnt,
                                      W1b, W2b, W3b, WtPh, WtPl, WtFh, WtFl);

    if (ws_size >= need_fast) {
        k_mix_prep<true><<<NN / 16, 512, 73728, stream>>>(X, WtPh, WtPl, Y, Ybf);
        k_scan<<<1, 256, 0, stream>>>(cnt, offs, cur);
        k_fill<<<EE / 256, 256, 0, stream>>>(EI, cur, EIDS, DSTS);
        k_edge_mfma<<<EE / 32, 512, 0, stream>>>(EA, CH, EW, EI, EIDS,
                                                 W1b, b1, W2b, b2, W3b, b3, XC);
        k_gather<<<NN, 128, 0, stream>>>(XC, Ybf, offs, DSTS, MSGb);
        k_mix_fin<short, short><<<NN / 16, 512, 73728, stream>>>(
            X, Ybf, MSGb, WtFh, WtFl, out);
    } else {
        k_mix_prep<false><<<NN / 16, 512, 73728, stream>>>(X, WtPh, WtPl, Y, Ybf);
        hipMemsetAsync(MSG, 0, (size_t)9 * NH * sizeof(float), stream);
        k_edge_atomic<<<EE / 32, 256, 0, stream>>>(EA, CH, EW, EI,
                                                   W1, b1, W2, b2, W3, b3, Y, MSG);
        k_mix_fin<float, float><<<NN / 16, 512, 73728, stream>>>(
            X, Y, MSG, WtFh, WtFl, out);
    }
}

// Round 21
// 284.309 us; speedup vs baseline: 1.0887x; 1.0883x over previous
//
#include <hip/hip_runtime.h>

#define NN  10000
#define HD  128
#define EE  160000
#define RD  32
#define NH  (NN * HD)

typedef __attribute__((ext_vector_type(8))) short short8_t;
typedef __attribute__((ext_vector_type(4))) float f32x4_t;
typedef __attribute__((ext_vector_type(4))) int   int4_t;

// fast silu: v_rcp_f32 (~1ulp) instead of exact-div sequence
__device__ __forceinline__ float silu_f(float z) {
    return z * __builtin_amdgcn_rcpf(1.0f + __expf(-z));
}
__device__ __forceinline__ short f2b(float v) {   // RNE fp32->bf16
    unsigned u = __float_as_uint(v);
    unsigned r = (u + 0x7FFFu + ((u >> 16) & 1u)) >> 16;
    return (short)r;
}
__device__ __forceinline__ float b2f(short s) {
    return __uint_as_float(((unsigned)(unsigned short)s) << 16);
}
// HW packed convert: bits[15:0]=bf16(a), bits[31:16]=bf16(b), RNE.
__device__ __forceinline__ unsigned cvt_pk(float a, float b) {
    unsigned r;
    asm("v_cvt_pk_bf16_f32 %0, %1, %2" : "=v"(r) : "v"(a), "v"(b));
    return r;
}
__device__ __forceinline__ float ldy(const float* p) { return *p; }
__device__ __forceinline__ float ldy(const short* p) { return b2f(*p); }

// ---------------------------------------------------------------------------
// Weight conversion + edge histogram folded into tail blocks (grid 1553).
// ---------------------------------------------------------------------------
__global__ __launch_bounds__(256) void k_wconv(
    const float* __restrict__ W1, const float* __restrict__ W2,
    const float* __restrict__ W3,
    const float* __restrict__ Wt0, const float* __restrict__ Wt1,
    const float* __restrict__ Wt2, const float* __restrict__ Wt3,
    const float* __restrict__ Wt4, const float* __restrict__ Wt5,
    const int* __restrict__ EI,   int* __restrict__ cnt,
    short* __restrict__ W1b, short* __restrict__ W2b, short* __restrict__ W3b,
    short* __restrict__ WtPh, short* __restrict__ WtPl,
    short* __restrict__ WtFh, short* __restrict__ WtFl)
{
    if (blockIdx.x >= 928) {              // histogram tail: 625 blocks
        const int e = (blockIdx.x - 928) * 256 + threadIdx.x;
        atomicAdd(&cnt[EI[e]], 1);
        return;
    }
    const int i = blockIdx.x * 256 + threadIdx.x;
    if (i < 8192) {                       // layer1: ct<8, kb<2, K_in=34
        const int j = i & 7, lane = (i >> 3) & 63;
        const int kb = (i >> 9) & 1, ct = i >> 10;
        const int n = ct * 16 + (lane & 15);
        const int k = kb * 32 + (lane >> 4) * 8 + j;
        W1b[i] = (k < 34) ? f2b(W1[n * 34 + k]) : (short)0;
        return;
    }
    int j2 = i - 8192;
    if (j2 < 32768) {                     // layer2: ct<16, kb<4, K_in=128
        const int j = j2 & 7, lane = (j2 >> 3) & 63;
        const int kb = (j2 >> 9) & 3, ct = j2 >> 11;
        const int n = ct * 16 + (lane & 15);
        const int k = kb * 32 + (lane >> 4) * 8 + j;
        W2b[j2] = f2b(W2[n * 128 + k]);
        return;
    }
    j2 -= 32768;
    if (j2 < 98304) {                     // layer3: ct<24, kb<8, K_in=256
        const int j = j2 & 7, lane = (j2 >> 3) & 63;
        const int kb = (j2 >> 9) & 7, ct = j2 >> 12;
        const int n = ct * 16 + (lane & 15);
        const int k = kb * 32 + (lane >> 4) * 8 + j;
        W3b[j2] = f2b(W3[n * 256 + k]);
        return;
    }
    j2 -= 98304;
    if (j2 < 6 * 16384) {
        const int m = j2 >> 14, idx = j2 & 16383;
        const float* src = (m == 0) ? Wt0 : (m == 1) ? Wt1 : (m == 2) ? Wt2
                         : (m == 3) ? Wt3 : (m == 4) ? Wt4 : Wt5;
        const float w = src[idx];
        const short hi = f2b(w);
        const short lo = f2b(w - b2f(hi));
        if (m < 3) { WtPh[m * 16384 + idx] = hi; WtPl[m * 16384 + idx] = lo; }
        else       { WtFh[(m - 3) * 16384 + idx] = hi; WtFl[(m - 3) * 16384 + idx] = lo; }
    }
}

// ---------------------------------------------------------------------------
// k_mix_prep<YBF16>: decompose X, channel-mix with WtP (hi/lo split).
// ---------------------------------------------------------------------------
template <bool YBF16>
__global__ __launch_bounds__(512, 4) void k_mix_prep(
    const float* __restrict__ X,
    const short* __restrict__ Wh, const short* __restrict__ Wl,
    float* __restrict__ Yf, short* __restrict__ ybf)
{
    extern __shared__ __align__(16) char smem[];   // 73728 B
    short* sBh = (short*)smem;
    short* sBl = sBh + 144 * 128;
    float* sC  = (float*)smem;

    const int tid = threadIdx.x;
    const int n0  = blockIdx.x * 16;

#pragma unroll 2
    for (int i = 0; i < 4; i++) {
        const int p  = i * 512 + tid;
        const int nl = p >> 7, h = p & 127;
        const float* t = X + ((size_t)((n0 + nl) * HD + h)) * 9;
        float T[9];
#pragma unroll
        for (int q = 0; q < 9; q++) T[q] = t[q];
        float nrm = 0.f;
#pragma unroll
        for (int q = 0; q < 9; q++) nrm = fmaf(T[q], T[q], nrm);
        const float inv = 1.0f / (nrm + 1.0f);
#pragma unroll
        for (int q = 0; q < 9; q++) T[q] *= inv;
        const float I = (T[0] + T[4] + T[8]) * (1.0f / 3.0f);
        float dec[9];
        dec[0] = I;
        dec[1] = 0.5f * (T[7] - T[5]);
        dec[2] = 0.5f * (T[2] - T[6]);
        dec[3] = 0.5f * (T[3] - T[1]);
        dec[4] = T[0] - I;
        dec[5] = 0.5f * (T[1] + T[3]);
        dec[6] = 0.5f * (T[2] + T[6]);
        dec[7] = T[4] - I;
        dec[8] = 0.5f * (T[5] + T[7]);
        const int sw = (nl & 7) << 3;
        const int hx = h ^ sw;
#pragma unroll
        for (int c = 0; c < 9; c++) {
            const float v  = dec[c];
            const short hi = f2b(v);
            const short lo = f2b(v - b2f(hi));
            const int idx = (c * 16 + nl) * 128 + hx;
            sBh[idx] = hi;
            sBl[idx] = lo;
        }
    }
    __syncthreads();

    const int lane = tid & 63, wid = tid >> 6;
    const int l15 = lane & 15, g = lane >> 4;
    f32x4_t acc[9];
#pragma unroll
    for (int c = 0; c < 9; c++) acc[c] = {0.f, 0.f, 0.f, 0.f};

    const int bsw = (l15 & 7) << 3;
    const int o   = wid * 16 + l15;
#pragma unroll
    for (int k = 0; k < 4; k++) {
        const int k0  = k * 32 + g * 8;
        const int ksw = k0 ^ bsw;
#pragma unroll
        for (int w = 0; w < 3; w++) {
            const size_t aoff = (size_t)w * 16384 + (size_t)o * 128 + k0;
            const short8_t Ah = *(const short8_t*)(Wh + aoff);
            const short8_t Al = *(const short8_t*)(Wl + aoff);
            const int ct0 = (w == 0) ? 0 : (w == 1 ? 1 : 4);
            const int ctn = (w == 0) ? 1 : (w == 1 ? 3 : 5);
            for (int cc = 0; cc < ctn; cc++) {
                const int ct = ct0 + cc;
                const int boff = (ct * 16 + l15) * 128 + ksw;
                const short8_t Bh = *(const short8_t*)&sBh[boff];
                const short8_t Bl = *(const short8_t*)&sBl[boff];
                acc[ct] = __builtin_amdgcn_mfma_f32_16x16x32_bf16(Al, Bh, acc[ct], 0, 0, 0);
                acc[ct] = __builtin_amdgcn_mfma_f32_16x16x32_bf16(Ah, Bl, acc[ct], 0, 0, 0);
                acc[ct] = __builtin_amdgcn_mfma_f32_16x16x32_bf16(Ah, Bh, acc[ct], 0, 0, 0);
            }
        }
    }
    __syncthreads();

    const int csw = (l15 & 7) << 2;
    {
        const int o0 = wid * 16 + g * 4;
#pragma unroll
        for (int ct = 0; ct < 9; ct++)
            *(f32x4_t*)&sC[(ct * 16 + l15) * 128 + (o0 ^ csw)] = acc[ct];
    }
    __syncthreads();

    for (int i = tid; i < 144 * 32; i += 512) {
        const int row = i >> 5, q = i & 31;
        const int c = row >> 4, nl = row & 15;
        const int sw = (nl & 7) << 2;
        const f32x4_t v = *(const f32x4_t*)&sC[row * 128 + ((q * 4) ^ sw)];
        const size_t oo = (size_t)c * NH + (size_t)(n0 + nl) * HD + q * 4;
        if constexpr (YBF16) {
            uint2 u;
            u.x = cvt_pk(v[0], v[1]);
            u.y = cvt_pk(v[2], v[3]);
            *(uint2*)&ybf[oo] = u;
        } else {
            *(f32x4_t*)&Yf[oo] = v;
        }
    }
}

// ---------------------------------------------------------------------------
// k_mix_fin<YT, MT>: M = msg*Y + Y*msg; decompose/normalize; mix WtF; out.
// ---------------------------------------------------------------------------
template <typename YT, typename MT>
__global__ __launch_bounds__(512, 4) void k_mix_fin(
    const float* __restrict__ X,
    const YT* __restrict__ Yp, const MT* __restrict__ Mp,
    const short* __restrict__ Wh, const short* __restrict__ Wl,
    float* __restrict__ outp)
{
    extern __shared__ __align__(16) char smem[];   // 73728 B
    short* sBh = (short*)smem;
    short* sBl = sBh + 144 * 128;
    float* sC  = (float*)smem;

    const int tid = threadIdx.x;
    const int n0  = blockIdx.x * 16;

#pragma unroll 2
    for (int i = 0; i < 4; i++) {
        const int p  = i * 512 + tid;
        const int nl = p >> 7, h = p & 127;
        const int basep = (n0 + nl) * HD + h;
        float yv[9], mv[9];
#pragma unroll
        for (int c = 0; c < 9; c++) {
            yv[c] = ldy(Yp + (size_t)c * NH + basep);
            mv[c] = ldy(Mp + (size_t)c * NH + basep);
        }
        float Yt[9], G[9];
        {
            const float I = yv[0], a0 = yv[1], a1 = yv[2], a2 = yv[3];
            const float s00 = yv[4], s01 = yv[5], s02 = yv[6], s11 = yv[7], s12 = yv[8];
            const float s22 = -s00 - s11;
            Yt[0] = I + s00; Yt[1] = s01 - a2; Yt[2] = s02 + a1;
            Yt[3] = s01 + a2; Yt[4] = I + s11; Yt[5] = s12 - a0;
            Yt[6] = s02 - a1; Yt[7] = s12 + a0; Yt[8] = I + s22;
        }
        {
            const float I = mv[0], a0 = mv[1], a1 = mv[2], a2 = mv[3];
            const float s00 = mv[4], s01 = mv[5], s02 = mv[6], s11 = mv[7], s12 = mv[8];
            const float s22 = -s00 - s11;
            G[0] = I + s00; G[1] = s01 - a2; G[2] = s02 + a1;
            G[3] = s01 + a2; G[4] = I + s11; G[5] = s12 - a0;
            G[6] = s02 - a1; G[7] = s12 + a0; G[8] = I + s22;
        }
        float M[9];
#pragma unroll
        for (int r = 0; r < 3; r++)
#pragma unroll
            for (int cc = 0; cc < 3; cc++) {
                float a = 0.f;
#pragma unroll
                for (int k = 0; k < 3; k++)
                    a += G[r * 3 + k] * Yt[k * 3 + cc]
                       + Yt[r * 3 + k] * G[k * 3 + cc];
                M[r * 3 + cc] = a;
            }
        const float I2 = (M[0] + M[4] + M[8]) * (1.0f / 3.0f);
        const float a0 = 0.5f * (M[7] - M[5]);
        const float a1 = 0.5f * (M[2] - M[6]);
        const float a2 = 0.5f * (M[3] - M[1]);
        const float s00 = M[0] - I2, s11 = M[4] - I2;
        const float s01 = 0.5f * (M[1] + M[3]);
        const float s02 = 0.5f * (M[2] + M[6]);
        const float s12 = 0.5f * (M[5] + M[7]);
        const float s22 = -s00 - s11;
        const float nrm = 2.f * (a0 * a0 + a1 * a1 + a2 * a2)
                        + (s00 * s00 + s11 * s11 + s22 * s22)
                        + 2.f * (s01 * s01 + s02 * s02 + s12 * s12)
                        + 3.f * I2 * I2;
        const float inv = 1.0f / (nrm + 1.0f);
        float dec[9];
        dec[0] = I2 * inv;  dec[1] = a0 * inv;  dec[2] = a1 * inv;
        dec[3] = a2 * inv;  dec[4] = s00 * inv; dec[5] = s01 * inv;
        dec[6] = s02 * inv; dec[7] = s11 * inv; dec[8] = s12 * inv;

        const int sw = (nl & 7) << 3;
        const int hx = h ^ sw;
#pragma unroll
        for (int c = 0; c < 9; c++) {
            const float v  = dec[c];
            const short hi = f2b(v);
            const short lo = f2b(v - b2f(hi));
            const int idx = (c * 16 + nl) * 128 + hx;
            sBh[idx] = hi;
            sBl[idx] = lo;
        }
    }
    __syncthreads();

    const int lane = tid & 63, wid = tid >> 6;
    const int l15 = lane & 15, g = lane >> 4;
    f32x4_t acc[9];
#pragma unroll
    for (int c = 0; c < 9; c++) acc[c] = {0.f, 0.f, 0.f, 0.f};

    const int bsw = (l15 & 7) << 3;
    const int o   = wid * 16 + l15;
#pragma unroll
    for (int k = 0; k < 4; k++) {
        const int k0  = k * 32 + g * 8;
        const int ksw = k0 ^ bsw;
#pragma unroll
        for (int w = 0; w < 3; w++) {
            const size_t aoff = (size_t)w * 16384 + (size_t)o * 128 + k0;
            const short8_t Ah = *(const short8_t*)(Wh + aoff);
            const short8_t Al = *(const short8_t*)(Wl + aoff);
            const int ct0 = (w == 0) ? 0 : (w == 1 ? 1 : 4);
            const int ctn = (w == 0) ? 1 : (w == 1 ? 3 : 5);
            for (int cc = 0; cc < ctn; cc++) {
                const int ct = ct0 + cc;
                const int boff = (ct * 16 + l15) * 128 + ksw;
                const short8_t Bh = *(const short8_t*)&sBh[boff];
                const short8_t Bl = *(const short8_t*)&sBl[boff];
                acc[ct] = __builtin_amdgcn_mfma_f32_16x16x32_bf16(Al, Bh, acc[ct], 0, 0, 0);
                acc[ct] = __builtin_amdgcn_mfma_f32_16x16x32_bf16(Ah, Bl, acc[ct], 0, 0, 0);
                acc[ct] = __builtin_amdgcn_mfma_f32_16x16x32_bf16(Ah, Bh, acc[ct], 0, 0, 0);
            }
        }
    }
    __syncthreads();

    const int csw = (l15 & 7) << 2;
    {
        const int o0 = wid * 16 + g * 4;
#pragma unroll
        for (int ct = 0; ct < 9; ct++)
            *(f32x4_t*)&sC[(ct * 16 + l15) * 128 + (o0 ^ csw)] = acc[ct];
    }
    __syncthreads();

#pragma unroll 2
    for (int i = 0; i < 4; i++) {
        const int p  = i * 512 + tid;
        const int nl = p >> 7, oo = p & 127;
        const int sw = (nl & 7) << 2;
        const int ox = oo ^ sw;
        float a9[9];
#pragma unroll
        for (int c = 0; c < 9; c++) a9[c] = sC[(c * 16 + nl) * 128 + ox];
        float D[9];
        {
            const float I = a9[0], a0 = a9[1], a1 = a9[2], a2 = a9[3];
            const float s00 = a9[4], s01 = a9[5], s02 = a9[6];
            const float s11 = a9[7], s12 = a9[8];
            const float s22 = -s00 - s11;
            D[0] = I + s00; D[1] = s01 - a2; D[2] = s02 + a1;
            D[3] = s01 + a2; D[4] = I + s11; D[5] = s12 - a0;
            D[6] = s02 - a1; D[7] = s12 + a0; D[8] = I + s22;
        }
        const size_t xbase = ((size_t)((n0 + nl) * HD + oo)) * 9;
        float T[9];
#pragma unroll
        for (int q = 0; q < 9; q++) T[q] = X[xbase + q];
        float nrm = 0.f;
#pragma unroll
        for (int q = 0; q < 9; q++) nrm = fmaf(T[q], T[q], nrm);
        const float inv = 1.0f / (nrm + 1.0f);
        float* op = outp + xbase;
#pragma unroll
        for (int r = 0; r < 3; r++)
#pragma unroll
            for (int cc = 0; cc < 3; cc++) {
                float dd2 = 0.f;
#pragma unroll
                for (int k = 0; k < 3; k++)
                    dd2 = fmaf(D[r * 3 + k], D[k * 3 + cc], dd2);
                op[r * 3 + cc] = T[r * 3 + cc] * inv + D[r * 3 + cc] + dd2;
            }
    }
}

// ---------------------------------------------------------------------------
// CSR scan + fill.
// ---------------------------------------------------------------------------
__global__ __launch_bounds__(256) void k_scan(const int* __restrict__ cnt,
                                              int* __restrict__ offs,
                                              int* __restrict__ cur)
{
    __shared__ int part[256];
    const int tid = threadIdx.x;
    const int per = (NN + 255) / 256;
    int s = 0;
    for (int i = 0; i < per; i++) {
        const int idx = tid * per + i;
        if (idx < NN) s += cnt[idx];
    }
    part[tid] = s;
    __syncthreads();
    if (tid == 0) {
        int r = 0;
        for (int i = 0; i < 256; i++) { const int t = part[i]; part[i] = r; r += t; }
        offs[NN] = r;
    }
    __syncthreads();
    int run = part[tid];
    for (int i = 0; i < per; i++) {
        const int idx = tid * per + i;
        if (idx < NN) {
            offs[idx] = run;
            cur[idx]  = run;
            run += cnt[idx];
        }
    }
}

__global__ __launch_bounds__(256) void k_fill(const int* __restrict__ EI,
                                              int* __restrict__ cur,
                                              int* __restrict__ EIDS,
                                              int* __restrict__ DSTS)
{
    const int e = blockIdx.x * 256 + threadIdx.x;
    const int s = EI[e];
    const int pos = atomicAdd(&cur[s], 1);
    EIDS[pos] = e;
    DSTS[pos] = EI[EE + e];
}

// ---------------------------------------------------------------------------
// Kernel 2: MFMA edge MLP, CSR-ordered, 64 edges/block (proven optimum).
// ---------------------------------------------------------------------------
__global__ __launch_bounds__(512, 4) void k_edge_mfma(
    const float* __restrict__ EA, const float* __restrict__ CH,
    const float* __restrict__ EW, const int*   __restrict__ EI,
    const int*   __restrict__ EIDS,
    const short* __restrict__ W1b, const float* __restrict__ b1,
    const short* __restrict__ W2b, const float* __restrict__ b2,
    const short* __restrict__ W3b, const float* __restrict__ b3,
    short* __restrict__ XC)
{
    __shared__ __align__(16) short sH2[64 * 256];   // 32 KB; first 8 KB = sIn
    __shared__ __align__(16) short sH1[64 * 128];   // 16 KB
    __shared__ float sCut[64];
    __shared__ int   sEid[64];

    short* sIn = sH2;
    const int tid = threadIdx.x;
    const int e0  = blockIdx.x * 64;

    {
        int4_t z = {0, 0, 0, 0};
        ((int4_t*)sIn)[tid] = z;
        if (tid < 64) sEid[tid] = EIDS[e0 + tid];
    }
    __syncthreads();
    {
        const int ee  = tid >> 3;
        const int eid = sEid[ee];
        const float4 v = *(const float4*)(EA + (size_t)eid * RD + (tid & 7) * 4);
        const int k = (tid & 7) * 4;
        short4 sv;
        sv.x = f2b(v.x); sv.y = f2b(v.y); sv.z = f2b(v.z); sv.w = f2b(v.w);
        *(short4*)&sIn[ee * 64 + (k ^ ((ee & 7) << 3))] = sv;
        if (tid < 64) {
            const int e2  = tid;
            const int eid2 = sEid[e2];
            const int s = EI[eid2];
            const int d = EI[EE + eid2];
            const int sw = (e2 & 7) << 3;
            sIn[e2 * 64 + (32 ^ sw)] = f2b(CH[s]);
            sIn[e2 * 64 + (33 ^ sw)] = f2b(CH[d]);
            const float w = EW[eid2];
            sCut[e2] = (w < 5.0f)
                     ? 0.5f * (__cosf(0.62831853071795864769f * w) + 1.0f) : 0.0f;
        }
    }
    __syncthreads();

    const int lane = tid & 63;
    const int wid  = tid >> 6;
    const int l15  = lane & 15;
    const int g    = lane >> 4;
    const int fsw  = l15 << 3;

    // ---- layer 1 ----
    {
        short8_t E1[4][2];
#pragma unroll
        for (int at = 0; at < 4; at++) {
            const int row = at * 16 + l15;
            const int x = (row & 7) << 3;
            E1[at][0] = *(const short8_t*)&sIn[row * 64 + ((g * 8) ^ x)];
            E1[at][1] = *(const short8_t*)&sIn[row * 64 + ((32 + g * 8) ^ x)];
        }
        const int ct = wid;
        const float4 b4 = *(const float4*)&b1[ct * 16 + g * 4];
        const short8_t av0 = *(const short8_t*)(W1b + (size_t)((ct * 2 + 0) * 64 + lane) * 8);
        const short8_t av1 = *(const short8_t*)(W1b + (size_t)((ct * 2 + 1) * 64 + lane) * 8);
        const int fcol = ct * 16 + g * 4;
#pragma unroll
        for (int at = 0; at < 4; at++) {
            f32x4_t acc = {b4.x, b4.y, b4.z, b4.w};
            acc = __builtin_amdgcn_mfma_f32_16x16x32_bf16(av0, E1[at][0], acc, 0, 0, 0);
            acc = __builtin_amdgcn_mfma_f32_16x16x32_bf16(av1, E1[at][1], acc, 0, 0, 0);
            const int edge = at * 16 + l15;
            uint2 u;
            u.x = cvt_pk(silu_f(acc[0]), silu_f(acc[1]));
            u.y = cvt_pk(silu_f(acc[2]), silu_f(acc[3]));
            *(uint2*)&sH1[edge * 128 + (fcol ^ fsw)] = u;
        }
    }
    __syncthreads();

    // ---- layer 2 ----
    {
        short8_t E2[4][4];
#pragma unroll
        for (int at = 0; at < 4; at++) {
            const int row = at * 16 + l15;
            const int x = (row & 15) << 3;
#pragma unroll
            for (int kb = 0; kb < 4; kb++)
                E2[at][kb] = *(const short8_t*)&sH1[row * 128 + ((kb * 32 + g * 8) ^ x)];
        }
#pragma unroll
        for (int c = 0; c < 2; c++) {
            const int ct = c * 8 + wid;
            const float4 b4 = *(const float4*)&b2[ct * 16 + g * 4];
            const int fcol = ct * 16 + g * 4;
            f32x4_t acc[4];
#pragma unroll
            for (int at = 0; at < 4; at++) acc[at] = {b4.x, b4.y, b4.z, b4.w};
#pragma unroll
            for (int kb = 0; kb < 4; kb++) {
                const short8_t av = *(const short8_t*)(W2b + (size_t)((ct * 4 + kb) * 64 + lane) * 8);
#pragma unroll
                for (int at = 0; at < 4; at++)
                    acc[at] = __builtin_amdgcn_mfma_f32_16x16x32_bf16(av, E2[at][kb], acc[at], 0, 0, 0);
            }
#pragma unroll
            for (int at = 0; at < 4; at++) {
                const int edge = at * 16 + l15;
                uint2 u;
                u.x = cvt_pk(silu_f(acc[at][0]), silu_f(acc[at][1]));
                u.y = cvt_pk(silu_f(acc[at][2]), silu_f(acc[at][3]));
                *(uint2*)&sH2[edge * 256 + (fcol ^ fsw)] = u;
            }
        }
    }
    __syncthreads();

    // ---- layer 3 ----
    {
        short8_t E3[4][8];
#pragma unroll
        for (int at = 0; at < 4; at++) {
            const int row = at * 16 + l15;
            const int x = (row & 15) << 3;
#pragma unroll
            for (int kb = 0; kb < 8; kb++)
                E3[at][kb] = *(const short8_t*)&sH2[row * 256 + ((kb * 32 + g * 8) ^ x)];
        }
        float cut[4];
#pragma unroll
        for (int at = 0; at < 4; at++) cut[at] = sCut[at * 16 + l15];
        for (int c = 0; c < 3; c++) {
            const int ct = c * 8 + wid;
            const float4 b4 = *(const float4*)&b3[ct * 16 + g * 4];
            const int fcol = ct * 16 + g * 4;
            f32x4_t acc[4];
#pragma unroll
            for (int at = 0; at < 4; at++) acc[at] = {b4.x, b4.y, b4.z, b4.w};
#pragma unroll
            for (int kb = 0; kb < 8; kb++) {
                const short8_t av = *(const short8_t*)(W3b + (size_t)((ct * 8 + kb) * 64 + lane) * 8);
#pragma unroll
                for (int at = 0; at < 4; at++)
                    acc[at] = __builtin_amdgcn_mfma_f32_16x16x32_bf16(av, E3[at][kb], acc[at], 0, 0, 0);
            }
#pragma unroll
            for (int at = 0; at < 4; at++) {
                const int edge = at * 16 + l15;
                const float cv = cut[at];
                uint2 u;
                u.x = cvt_pk(silu_f(acc[at][0]) * cv, silu_f(acc[at][1]) * cv);
                u.y = cvt_pk(silu_f(acc[at][2]) * cv, silu_f(acc[at][3]) * cv);
                *(uint2*)&XC[(size_t)(e0 + edge) * 384 + fcol] = u;
            }
        }
    }
}

// ---------------------------------------------------------------------------
// Kernel 2b: node-major gather, p-loop unrolled x2 (round-16 proven form).
// ---------------------------------------------------------------------------
__global__ __launch_bounds__(256) void k_gather(
    const short* __restrict__ XC, const short* __restrict__ Y,
    const int* __restrict__ offs, const int* __restrict__ DSTS,
    short* __restrict__ MSGb)
{
    const int tid = threadIdx.x;
    const int nl  = tid >> 7, h = tid & 127;
    const int n   = blockIdx.x * 2 + nl;
    const int beg = offs[n], end = offs[n + 1];

    float m[9];
#pragma unroll
    for (int c = 0; c < 9; c++) m[c] = 0.f;

    int p = beg;
    for (; p + 2 <= end; p += 2) {
        const int dst0 = DSTS[p];
        const int dst1 = DSTS[p + 1];
        const size_t xb0 = (size_t)p * 384;
        const size_t xb1 = (size_t)(p + 1) * 384;
        const float x00 = b2f(XC[xb0 + h]);
        const float x01 = b2f(XC[xb0 + 128 + h]);
        const float x02 = b2f(XC[xb0 + 256 + h]);
        const float x10 = b2f(XC[xb1 + h]);
        const float x11 = b2f(XC[xb1 + 128 + h]);
        const float x12 = b2f(XC[xb1 + 256 + h]);
        const int yb0 = dst0 * HD + h;
        const int yb1 = dst1 * HD + h;
        float y0[9], y1[9];
#pragma unroll
        for (int c = 0; c < 9; c++) {
            y0[c] = b2f(Y[(size_t)c * NH + yb0]);
            y1[c] = b2f(Y[(size_t)c * NH + yb1]);
        }
        m[0] = fmaf(x00, y0[0], m[0]);  m[0] = fmaf(x10, y1[0], m[0]);
        m[1] = fmaf(x01, y0[1], m[1]);  m[1] = fmaf(x11, y1[1], m[1]);
        m[2] = fmaf(x01, y0[2], m[2]);  m[2] = fmaf(x11, y1[2], m[2]);
        m[3] = fmaf(x01, y0[3], m[3]);  m[3] = fmaf(x11, y1[3], m[3]);
        m[4] = fmaf(x02, y0[4], m[4]);  m[4] = fmaf(x12, y1[4], m[4]);
        m[5] = fmaf(x02, y0[5], m[5]);  m[5] = fmaf(x12, y1[5], m[5]);
        m[6] = fmaf(x02, y0[6], m[6]);  m[6] = fmaf(x12, y1[6], m[6]);
        m[7] = fmaf(x02, y0[7], m[7]);  m[7] = fmaf(x12, y1[7], m[7]);
        m[8] = fmaf(x02, y0[8], m[8]);  m[8] = fmaf(x12, y1[8], m[8]);
    }
    for (; p < end; ++p) {
        const int dst = DSTS[p];
        const size_t xb = (size_t)p * 384;
        const float x0 = b2f(XC[xb + h]);
        const float x1 = b2f(XC[xb + 128 + h]);
        const float x2 = b2f(XC[xb + 256 + h]);
        const int yb = dst * HD + h;
        m[0] = fmaf(x0, b2f(Y[0 * (size_t)NH + yb]), m[0]);
        m[1] = fmaf(x1, b2f(Y[1 * (size_t)NH + yb]), m[1]);
        m[2] = fmaf(x1, b2f(Y[2 * (size_t)NH + yb]), m[2]);
        m[3] = fmaf(x1, b2f(Y[3 * (size_t)NH + yb]), m[3]);
        m[4] = fmaf(x2, b2f(Y[4 * (size_t)NH + yb]), m[4]);
        m[5] = fmaf(x2, b2f(Y[5 * (size_t)NH + yb]), m[5]);
        m[6] = fmaf(x2, b2f(Y[6 * (size_t)NH + yb]), m[6]);
        m[7] = fmaf(x2, b2f(Y[7 * (size_t)NH + yb]), m[7]);
        m[8] = fmaf(x2, b2f(Y[8 * (size_t)NH + yb]), m[8]);
    }
    const int base = n * HD + h;
#pragma unroll
    for (int c = 0; c < 9; c++) MSGb[(size_t)c * NH + base] = f2b(m[c]);
}

// ---------------------------------------------------------------------------
// Fallback (small ws): fused VALU edge MLP + atomic scatter (fp32 MSG).
// ---------------------------------------------------------------------------
__global__ __launch_bounds__(256) void k_edge_atomic(
    const float* __restrict__ EA, const float* __restrict__ CH,
    const float* __restrict__ EW, const int*   __restrict__ EI,
    const float* __restrict__ W1, const float* __restrict__ b1,
    const float* __restrict__ W2, const float* __restrict__ b2,
    const float* __restrict__ W3, const float* __restrict__ b3,
    const float* __restrict__ Y,  float* __restrict__ MSG)
{
    __shared__ __align__(16) float sInf[32 * 35];
    __shared__ __align__(16) float sH1f[32 * 132];
    __shared__ __align__(16) float sH2f[32 * 260];
    __shared__ __align__(16) float sXcf[32 * 132];
    __shared__ float sCc[32];
    __shared__ int   sS[32], sD[32];

    const int e0  = blockIdx.x * 32;
    const int tid = threadIdx.x;

    {
        const float4 v = ((const float4*)(EA + (size_t)e0 * RD))[tid];
        const int e = tid >> 3;
        const int k = (tid & 7) * 4;
        float* p = sInf + e * 35 + k;
        p[0] = v.x; p[1] = v.y; p[2] = v.z; p[3] = v.w;
    }
    if (tid < 32) {
        const int e = tid;
        const int s = EI[e0 + e];
        const int d = EI[EE + e0 + e];
        sS[e] = s; sD[e] = d;
        sInf[e * 35 + 32] = CH[s];
        sInf[e * 35 + 33] = CH[d];
        const float w = EW[e0 + e];
        sCc[e] = (w < 5.0f) ? 0.5f * (__cosf(0.62831853071795864769f * w) + 1.0f)
                            : 0.0f;
    }
    __syncthreads();

    const int e  = tid & 31;
    const int og = tid >> 5;

    {
        float acc[16];
#pragma unroll
        for (int j = 0; j < 16; j++) acc[j] = b1[og * 16 + j];
        for (int k = 0; k < 34; k++) {
            const float v = sInf[e * 35 + k];
#pragma unroll
            for (int j = 0; j < 16; j++)
                acc[j] = fmaf(v, W1[(og * 16 + j) * 34 + k], acc[j]);
        }
#pragma unroll
        for (int j = 0; j < 16; j++)
            sH1f[e * 132 + og * 16 + j] = silu_f(acc[j]);
    }
    __syncthreads();

    {
        float acc[32];
#pragma unroll
        for (int j = 0; j < 32; j++) acc[j] = b2[og * 32 + j];
        for (int hq = 0; hq < 32; hq++) {
            const float4 v = *(const float4*)&sH1f[e * 132 + hq * 4];
#pragma unroll
            for (int j = 0; j < 32; j++) {
                const float4 w =
                    *(const float4*)&W2[(size_t)(og * 32 + j) * 128 + hq * 4];
                acc[j] = fmaf(v.x, w.x, fmaf(v.y, w.y,
                         fmaf(v.z, w.z, fmaf(v.w, w.w, acc[j]))));
            }
        }
#pragma unroll
        for (int j = 0; j < 32; j++)
            sH2f[e * 260 + og * 32 + j] = silu_f(acc[j]);
    }
    __syncthreads();

    for (int c = 0; c < 3; c++) {
        {
            float acc[16];
#pragma unroll
            for (int j = 0; j < 16; j++) acc[j] = b3[c * 128 + og * 16 + j];
            for (int hq = 0; hq < 64; hq++) {
                const float4 v = *(const float4*)&sH2f[e * 260 + hq * 4];
#pragma unroll
                for (int j = 0; j < 16; j++) {
                    const float4 w = *(const float4*)
                        &W3[(size_t)(c * 128 + og * 16 + j) * 256 + hq * 4];
                    acc[j] = fmaf(v.x, w.x, fmaf(v.y, w.y,
                             fmaf(v.z, w.z, fmaf(v.w, w.w, acc[j]))));
                }
            }
            const float cc = sCc[e];
#pragma unroll
            for (int j = 0; j < 16; j++)
                sXcf[e * 132 + og * 16 + j] = silu_f(acc[j]) * cc;
        }
        __syncthreads();
        {
            const int h  = tid & 127;
            const int eh = tid >> 7;
#pragma unroll 4
            for (int i = 0; i < 16; i++) {
                const int ee = (eh << 4) | i;
                const int s = sS[ee], d = sD[ee];
                const float xv = sXcf[ee * 132 + h];
                const int sb = s * HD + h, db = d * HD + h;
                if (c == 0) {
                    atomicAdd(&MSG[0 * (size_t)NH + sb], xv * Y[0 * (size_t)NH + db]);
                } else if (c == 1) {
#pragma unroll
                    for (int cc2 = 1; cc2 < 4; cc2++)
                        atomicAdd(&MSG[(size_t)cc2 * NH + sb],
                                  xv * Y[(size_t)cc2 * NH + db]);
                } else {
#pragma unroll
                    for (int cc2 = 4; cc2 < 9; cc2++)
                        atomicAdd(&MSG[(size_t)cc2 * NH + sb],
                                  xv * Y[(size_t)cc2 * NH + db]);
                }
            }
        }
        __syncthreads();
    }
}

// ---------------------------------------------------------------------------
static inline size_t align_up(size_t v, size_t a) { return (v + a - 1) & ~(a - 1); }

extern "C" void kernel_launch(void* const* d_in, const int* in_sizes, int n_in,
                              void* d_out, int out_size, void* d_ws, size_t ws_size,
                              hipStream_t stream)
{
    const float* X   = (const float*)d_in[0];
    const float* CH  = (const float*)d_in[1];
    const float* EA  = (const float*)d_in[2];
    const float* EW  = (const float*)d_in[3];
    const float* W1  = (const float*)d_in[4];
    const float* b1  = (const float*)d_in[5];
    const float* W2  = (const float*)d_in[6];
    const float* b2  = (const float*)d_in[7];
    const float* W3  = (const float*)d_in[8];
    const float* b3  = (const float*)d_in[9];
    const float* Wt0 = (const float*)d_in[10];
    const float* Wt1 = (const float*)d_in[11];
    const float* Wt2 = (const float*)d_in[12];
    const float* Wt3 = (const float*)d_in[13];
    const float* Wt4 = (const float*)d_in[14];
    const float* Wt5 = (const float*)d_in[15];
    const int*   EI  = (const int*)d_in[16];
    float* out = (float*)d_out;

    size_t off = 0;
    float* Y    = (float*)((char*)d_ws + off); off = align_up(off + (size_t)9 * NH * 4, 64);
    float* MSG  = (float*)((char*)d_ws + off); off = align_up(off + (size_t)9 * NH * 4, 64);
    short* MSGb = (short*)MSG;   // alias: bf16 MSG planes (fast path)
    int*   cnt  = (int*)((char*)d_ws + off);   off = align_up(off + (size_t)NN * 4, 64);
    int*   cur  = (int*)((char*)d_ws + off);   off = align_up(off + (size_t)NN * 4, 64);
    int*   offs = (int*)((char*)d_ws + off);   off = align_up(off + (size_t)(NN + 1) * 4, 64);
    int*   EIDS = (int*)((char*)d_ws + off);   off = align_up(off + (size_t)EE * 4, 64);
    int*   DSTS = (int*)((char*)d_ws + off);   off = align_up(off + (size_t)EE * 4, 64);
    short* W1b  = (short*)((char*)d_ws + off); off = align_up(off + (size_t)8192 * 2, 64);
    short* W2b  = (short*)((char*)d_ws + off); off = align_up(off + (size_t)32768 * 2, 64);
    short* W3b  = (short*)((char*)d_ws + off); off = align_up(off + (size_t)98304 * 2, 64);
    short* WtPh = (short*)((char*)d_ws + off); off = align_up(off + (size_t)3 * 16384 * 2, 64);
    short* WtPl = (short*)((char*)d_ws + off); off = align_up(off + (size_t)3 * 16384 * 2, 64);
    short* WtFh = (short*)((char*)d_ws + off); off = align_up(off + (size_t)3 * 16384 * 2, 64);
    short* WtFl = (short*)((char*)d_ws + off); off = align_up(off + (size_t)3 * 16384 * 2, 64);
    short* XC   = (short*)((char*)d_ws + off); off = align_up(off + (size_t)EE * 384 * 2, 64);
    short* Ybf  = (short*)((char*)d_ws + off); off = align_up(off + (size_t)9 * NH * 2, 64);
    const size_t need_fast = off;

    hipMemsetAsync(cnt, 0, (size_t)NN * sizeof(int), stream);
    k_wconv<<<1553, 256, 0, stream>>>(W1, W2, W3, Wt0, Wt1, Wt2, Wt3, Wt4, Wt5,
                                      EI, cnt,
                                      W1b, W2b, W3b, WtPh, WtPl, WtFh, WtFl);

    if (ws_size >= need_fast) {
        k_mix_prep<true><<<NN / 16, 512, 73728, stream>>>(X, WtPh, WtPl, Y, Ybf);
        k_scan<<<1, 256, 0, stream>>>(cnt, offs, cur);
        k_fill<<<EE / 256, 256, 0, stream>>>(EI, cur, EIDS, DSTS);
        k_edge_mfma<<<EE / 64, 512, 0, stream>>>(EA, CH, EW, EI, EIDS,
                                                 W1b, b1, W2b, b2, W3b, b3, XC);
        k_gather<<<NN / 2, 256, 0, stream>>>(XC, Ybf, offs, DSTS, MSGb);
        k_mix_fin<short, short><<<NN / 16, 512, 73728, stream>>>(
            X, Ybf, MSGb, WtFh, WtFl, out);
    } else {
        k_mix_prep<false><<<NN / 16, 512, 73728, stream>>>(X, WtPh, WtPl, Y, Ybf);
        hipMemsetAsync(MSG, 0, (size_t)9 * NH * sizeof(float), stream);
        k_edge_atomic<<<EE / 32, 256, 0, stream>>>(EA, CH, EW, EI,
                                                   W1, b1, W2, b2, W3, b3, Y, MSG);
        k_mix_fin<float, float><<<NN / 16, 512, 73728, stream>>>(
            X, Y, MSG, WtFh, WtFl, out);
    }
}